// Round 17
// baseline (23873.810 us; speedup 1.0000x reference)
//
#include <hip/hip_runtime.h>

typedef unsigned short u16;
typedef __attribute__((ext_vector_type(8))) short short8;
typedef __attribute__((ext_vector_type(4))) short short4v;
typedef __attribute__((ext_vector_type(4))) float f32x4;
typedef __attribute__((ext_vector_type(8))) _Float16 h16x8;
typedef __attribute__((ext_vector_type(4))) _Float16 h16x4;

#define NB 256      // batch
#define TE 512      // encoder T
#define DK 256      // key dim
#define DV 256      // value dim
#define HH 512      // hidden
#define NV 35       // vocab
#define STEPS 300
#define TLEN 301
#define K1 1280     // LSTM1 inner dim: emb(512) + ctx(256) + h1(512)
#define K2 768      // LSTM2 inner dim: h1(512) + h2(256)

__device__ __forceinline__ float bf2f(u16 u){ return __uint_as_float(((unsigned)u)<<16); }
__device__ __forceinline__ u16 f2bf(float f){
  unsigned u = __float_as_uint(f);
  u += 0x7fffu + ((u>>16)&1u);   // RNE
  return (u16)(u>>16);
}
__device__ __forceinline__ void splitbf(float f, short& hi, short& lo){
  u16 h = f2bf(f);
  float r = f - bf2f(h);
  hi = (short)h; lo = (short)f2bf(r);
}
__device__ __forceinline__ float sigm(float x){ return 1.f/(1.f+expf(-x)); }

// Coherent loads: bypass L1 (sc0), read from XCD-shared L2. Used for all
// island-internal recurrent data (h1/h2/ctx + emb region of A). Producer
// stores are write-through L1 -> L2; __syncthreads drains vmcnt before the
// island flag release, so a consumer sc0 load after flag-observe is safe.
__device__ __forceinline__ float4 ld4c(const float* p){
  float4 r;
  asm volatile("global_load_dwordx4 %0, %1, off sc0\n\ts_waitcnt vmcnt(0)"
               : "=v"(r) : "v"(p) : "memory");
  return r;
}
__device__ __forceinline__ float ld1c(const float* p){
  float r;
  asm volatile("global_load_dword %0, %1, off sc0\n\ts_waitcnt vmcnt(0)"
               : "=v"(r) : "v"(p) : "memory");
  return r;
}

// ---------------- conversion kernels (once per launch) ----------------
__global__ void conv_cat_split(u16* __restrict__ dhi, u16* __restrict__ dlo,
                               const float* __restrict__ s1, const float* __restrict__ s2,
                               int k1, int k2, int total8){
  int i = blockIdx.x*blockDim.x + threadIdx.x;
  if (i >= total8) return;
  int ktot = k1 + k2;
  long e = (long)i*8;
  int r = (int)(e / ktot); int k = (int)(e - (long)r*ktot);
  const float* s = (k < k1) ? (s1 + (size_t)r*k1 + k) : (s2 + (size_t)r*k2 + (k-k1));
  short8 oh, ol;
  #pragma unroll
  for (int q=0;q<8;++q){ short h,l; splitbf(s[q],h,l); oh[q]=h; ol[q]=l; }
  *(short8*)(dhi + e) = oh;
  *(short8*)(dlo + e) = ol;
}

__global__ void conv_f16(u16* __restrict__ dst, const float* __restrict__ src, int n8){
  int i = blockIdx.x*blockDim.x + threadIdx.x;
  if (i >= n8) return;
  const float* s = src + (size_t)i*8;
  h16x8 o;
  #pragma unroll
  for (int q=0;q<8;++q) o[q] = (_Float16)s[q];
  *(h16x8*)(dst + (size_t)i*8) = o;
}

struct Params {
  const void *keys, *vals;       // f16 copies (or f32 originals)
  const int *text, *lens;
  const float *emb;
  const u16 *W1h, *W1l, *W2h, *W2l;
  const float *bi1, *bh1, *bi2, *bh2;
  const float *Wout, *bout;
  float *h1b, *h2b, *ctx, *out;
  unsigned *bar;                  // island barrier lines (8 x 256B)
  unsigned *reg;                  // island registration counters (8 x 256B)
};

// ============ XCD-island persistent kernel: all 300 steps ============
// 256 blocks x 512 thr, 1 block/CU (forced by >80KB LDS). Each physical XCD
// (read via HW_REG_XCC_ID) forms an island of exactly 32 blocks that owns
// batch rows [32*xcd, 32*xcd+32) for the whole recurrence. All sync is
// island-local (L2-coherent within an XCD); no cross-XCD communication.
template<bool F16>
__global__ __launch_bounds__(512) void decoder_k(Params P)
{
  __shared__ __align__(16) u16 AhS[2][4][16][8], AlS[2][4][16][8];   // 2KB each
  __shared__ __align__(16) u16 BhS[4][4][16][8], BlS[4][4][16][8];   // 4KB each
  __shared__ float gex[4][32][16];    // 8KB gate exchange
  __shared__ float h2s[DK];
  __shared__ float e_s[TE];
  __shared__ float ctx_s[DV];
  __shared__ float ctxp[8][DV];
  __shared__ float red_s[16];
  __shared__ int islS[2];

  const int tid = threadIdx.x;
  // -------- island registration (physical XCD id + slot) --------
  if (tid == 0){
    unsigned xcd = __builtin_amdgcn_s_getreg(20 | (0<<6) | ((8-1)<<11)) & 7u;  // HW_REG_XCC_ID
    unsigned slot = __hip_atomic_fetch_add(P.reg + xcd*64, 1u,
                      __ATOMIC_RELAXED, __HIP_MEMORY_SCOPE_AGENT);
    islS[0] = (int)xcd; islS[1] = (int)slot;
  }
  __syncthreads();
  const int isl = islS[0], slot = islS[1];     // isl 0..7, slot 0..31
  const int n0 = isl*32;                       // island's 32 batch rows
  unsigned* barL = P.bar + isl*64;             // 4 sub-counters at +0,+16,+32,+48

  const int w = tid>>6, l = tid&63;
  const int nh = w&1, gw = w>>1;               // MFMA wave role
  const bool isA = tid < 256;
  const int an = tid>>3, akq = tid&7;          // A staging: row, k-quad
  const int jl  = (tid-256)>>2;                // B staging
  const int koB = ((tid-256)&3)*8;
  const int gs = (jl>>4)&3, jhl = jl&15;
  const int en = tid>>4, ej = tid&15;          // epilogue cell

  const int jh0_1 = slot*16;                   // lstm1: 32 jh tiles
  const bool p2act = slot < 16;                // lstm2: 16 jh tiles
  const int jh0_2 = slot*16;

  float b1i = P.bi1[jh0_1+ej]      + P.bh1[jh0_1+ej];
  float b1f = P.bi1[HH+jh0_1+ej]   + P.bh1[HH+jh0_1+ej];
  float b1g = P.bi1[2*HH+jh0_1+ej] + P.bh1[2*HH+jh0_1+ej];
  float b1o = P.bi1[3*HH+jh0_1+ej] + P.bh1[3*HH+jh0_1+ej];
  float b2i=0.f,b2f=0.f,b2g=0.f,b2o=0.f;
  if (p2act){
    b2i = P.bi2[jh0_2+ej]      + P.bh2[jh0_2+ej];
    b2f = P.bi2[DK+jh0_2+ej]   + P.bh2[DK+jh0_2+ej];
    b2g = P.bi2[2*DK+jh0_2+ej] + P.bh2[2*DK+jh0_2+ej];
    b2o = P.bi2[3*DK+jh0_2+ej] + P.bh2[3*DK+jh0_2+ej];
  }
  // weight row pointers (read-only, cached; re-streamed from LLC per step)
  const u16 *pB1h = P.W1h + (size_t)(gs*512 + jh0_1 + jhl)*K1 + koB;
  const u16 *pB1l = P.W1l + (size_t)(gs*512 + jh0_1 + jhl)*K1 + koB;
  const u16 *pB2h = P.W2h + (size_t)(gs*256 + jh0_2 + jhl)*K2 + koB;
  const u16 *pB2l = P.W2l + (size_t)(gs*256 + jh0_2 + jhl)*K2 + koB;

  float c1r = 0.f, c2r = 0.f;                  // register cell state
  unsigned round = 0;

  // island barrier: 4 sub-counters x 8 arrivals; relaxed agent atomics.
  auto ibar = [&](unsigned rnd){
    __syncthreads();                            // drains stores (vmcnt 0)
    if (threadIdx.x == 0){
      __hip_atomic_fetch_add(barL + (slot>>3)*16, 1u,
                             __ATOMIC_RELAXED, __HIP_MEMORY_SCOPE_AGENT);
      #pragma unroll
      for (int q=0;q<4;++q){
        while (__hip_atomic_load(barL + q*16,
                 __ATOMIC_RELAXED, __HIP_MEMORY_SCOPE_AGENT) < 8u*rnd)
          __builtin_amdgcn_s_sleep(1);
      }
    }
    __syncthreads();
  };

  for (int t=0; t<STEPS; ++t){
    const int par = t&1;
    const float* h1_old = P.h1b + (size_t)par*NB*HH;
    float*       h1_new = P.h1b + (size_t)(par^1)*NB*HH;
    const float* h2_old = P.h2b + (size_t)par*NB*DK;
    float*       h2_new = P.h2b + (size_t)(par^1)*NB*DK;

    // ============ phase 1: LSTM1 (32 rows x 64 gate-cols, K=1280) ============
    {
      const float* aemb = nullptr; const float* actx = nullptr; const float* ah1 = nullptr;
      if (isA){
        int arow = n0 + an;
        aemb = P.emb + (size_t)P.text[arow*TLEN + t]*HH;
        actx = P.ctx + (size_t)arow*DV;
        ah1  = h1_old + (size_t)arow*HH;
      }
      f32x4 acc = {0.f,0.f,0.f,0.f};
      for (int k0=0; k0<K1; k0+=32){
        if (isA){
          int k = k0 + akq*4;
          const float* src = (k<512)? (aemb+k) : (k<768)? (actx+(k-512)) : (ah1+(k-768));
          float4 av = ld4c(src);
          short4v hv, lv; short h,s2;
          splitbf(av.x,h,s2); hv[0]=h; lv[0]=s2;
          splitbf(av.y,h,s2); hv[1]=h; lv[1]=s2;
          splitbf(av.z,h,s2); hv[2]=h; lv[2]=s2;
          splitbf(av.w,h,s2); hv[3]=h; lv[3]=s2;
          *(short4v*)&AhS[an>>4][akq>>1][an&15][(akq&1)*4] = hv;
          *(short4v*)&AlS[an>>4][akq>>1][an&15][(akq&1)*4] = lv;
        } else {
          *(short8*)&BhS[gs][koB>>3][jhl][0] = *(const short8*)(pB1h + k0);
          *(short8*)&BlS[gs][koB>>3][jhl][0] = *(const short8*)(pB1l + k0);
        }
        __syncthreads();
        short8 afh = *(const short8*)&AhS[nh][l>>4][l&15][0];
        short8 afl = *(const short8*)&AlS[nh][l>>4][l&15][0];
        short8 bfh = *(const short8*)&BhS[gw][l>>4][l&15][0];
        short8 bfl = *(const short8*)&BlS[gw][l>>4][l&15][0];
        acc = __builtin_amdgcn_mfma_f32_16x16x32_bf16(afh, bfh, acc, 0,0,0);
        acc = __builtin_amdgcn_mfma_f32_16x16x32_bf16(afl, bfh, acc, 0,0,0);
        acc = __builtin_amdgcn_mfma_f32_16x16x32_bf16(afh, bfl, acc, 0,0,0);
        __syncthreads();
      }
      #pragma unroll
      for (int r=0;r<4;++r) gex[gw][nh*16 + (l>>4)*4 + r][l&15] = acc[r];
      __syncthreads();
      {
        float iv = sigm(gex[0][en][ej] + b1i);
        float fv = sigm(gex[1][en][ej] + b1f);
        float gg = tanhf(gex[2][en][ej] + b1g);
        float ov = sigm(gex[3][en][ej] + b1o);
        float cn = fv*c1r + iv*gg;
        c1r = cn;
        h1_new[(size_t)(n0+en)*HH + jh0_1+ej] = ov*tanhf(cn);
      }
    }
    ++round; ibar(round);

    // ============ phase 2: LSTM2 (slots 0..15; 32 rows x 64 gate-cols, K=768) ============
    if (p2act){
      const float* ah1 = nullptr; const float* ah2 = nullptr;
      if (isA){
        int arow = n0 + an;
        ah1 = h1_new + (size_t)arow*HH;
        ah2 = h2_old + (size_t)arow*DK;
      }
      f32x4 acc = {0.f,0.f,0.f,0.f};
      for (int k0=0; k0<K2; k0+=32){
        if (isA){
          int k = k0 + akq*4;
          const float* src = (k<512)? (ah1+k) : (ah2+(k-512));
          float4 av = ld4c(src);
          short4v hv, lv; short h,s2;
          splitbf(av.x,h,s2); hv[0]=h; lv[0]=s2;
          splitbf(av.y,h,s2); hv[1]=h; lv[1]=s2;
          splitbf(av.z,h,s2); hv[2]=h; lv[2]=s2;
          splitbf(av.w,h,s2); hv[3]=h; lv[3]=s2;
          *(short4v*)&AhS[an>>4][akq>>1][an&15][(akq&1)*4] = hv;
          *(short4v*)&AlS[an>>4][akq>>1][an&15][(akq&1)*4] = lv;
        } else {
          *(short8*)&BhS[gs][koB>>3][jhl][0] = *(const short8*)(pB2h + k0);
          *(short8*)&BlS[gs][koB>>3][jhl][0] = *(const short8*)(pB2l + k0);
        }
        __syncthreads();
        short8 afh = *(const short8*)&AhS[nh][l>>4][l&15][0];
        short8 afl = *(const short8*)&AlS[nh][l>>4][l&15][0];
        short8 bfh = *(const short8*)&BhS[gw][l>>4][l&15][0];
        short8 bfl = *(const short8*)&BlS[gw][l>>4][l&15][0];
        acc = __builtin_amdgcn_mfma_f32_16x16x32_bf16(afh, bfh, acc, 0,0,0);
        acc = __builtin_amdgcn_mfma_f32_16x16x32_bf16(afl, bfh, acc, 0,0,0);
        acc = __builtin_amdgcn_mfma_f32_16x16x32_bf16(afh, bfl, acc, 0,0,0);
        __syncthreads();
      }
      #pragma unroll
      for (int r=0;r<4;++r) gex[gw][nh*16 + (l>>4)*4 + r][l&15] = acc[r];
      __syncthreads();
      {
        float iv = sigm(gex[0][en][ej] + b2i);
        float fv = sigm(gex[1][en][ej] + b2f);
        float gg = tanhf(gex[2][en][ej] + b2g);
        float ov = sigm(gex[3][en][ej] + b2o);
        float cn = fv*c2r + iv*gg;
        c2r = cn;
        h2_new[(size_t)(n0+en)*DK + jh0_2+ej] = ov*tanhf(cn);
      }
    }
    ++round; ibar(round);

    // ============ phase 3: attention + output (row n = n0 + slot) ============
    {
      const int n = n0 + slot;
      int L = P.lens[n] >> 3;
      if (tid < DK) h2s[tid] = ld1c(&h2_new[(size_t)n*DK + tid]);
      __syncthreads();
      float qreg[32];
      {
        int off = (l&7)*32;
        #pragma unroll
        for (int q=0;q<32;q+=4){
          float4 v4 = *(const float4*)&h2s[off+q];
          qreg[q]=v4.x; qreg[q+1]=v4.y; qreg[q+2]=v4.z; qreg[q+3]=v4.w;
        }
      }
      for (int r = w*8 + (l>>3); r < L; r += 64){
        float s = 0.f;
        if (F16){
          const u16* kr = (const u16*)P.keys + (size_t)(n*TE + r)*DK + (l&7)*32;
          #pragma unroll
          for (int q=0;q<32;q+=8){
            h16x8 kv = *(const h16x8*)(kr + q);
            s += (float)kv[0]*qreg[q+0] + (float)kv[1]*qreg[q+1]
               + (float)kv[2]*qreg[q+2] + (float)kv[3]*qreg[q+3]
               + (float)kv[4]*qreg[q+4] + (float)kv[5]*qreg[q+5]
               + (float)kv[6]*qreg[q+6] + (float)kv[7]*qreg[q+7];
          }
        } else {
          const float* kr = (const float*)P.keys + (size_t)(n*TE + r)*DK + (l&7)*32;
          #pragma unroll
          for (int q=0;q<32;q+=4){
            float4 kv = *(const float4*)(kr + q);
            s += kv.x*qreg[q] + kv.y*qreg[q+1] + kv.z*qreg[q+2] + kv.w*qreg[q+3];
          }
        }
        s += __shfl_xor(s,1); s += __shfl_xor(s,2); s += __shfl_xor(s,4);
        if ((l&7)==0) e_s[r] = s;
      }
      __syncthreads();
      float v = (tid < L) ? e_s[tid] : -1e30f;
      float m = v;
      #pragma unroll
      for (int o=1;o<64;o<<=1) m = fmaxf(m, __shfl_xor(m,o));
      if (l==0) red_s[w] = m;
      __syncthreads();
      m = red_s[0];
      #pragma unroll
      for (int q=1;q<8;++q) m = fmaxf(m, red_s[q]);
      float p = (tid < L) ? expf(v-m) : 0.f;
      float sm = p;
      #pragma unroll
      for (int o=1;o<64;o<<=1) sm += __shfl_xor(sm,o);
      if (l==0) red_s[8+w] = sm;
      __syncthreads();
      sm = red_s[8];
      #pragma unroll
      for (int q=1;q<8;++q) sm += red_s[8+q];
      e_s[tid] = p * (1.f/sm);
      __syncthreads();
      float4 cacc = {0.f,0.f,0.f,0.f};
      if (F16){
        const u16* vpb = (const u16*)P.vals + (size_t)n*TE*DV + l*4;
        for (int r = w; r < L; r += 8){
          float a = e_s[r];
          h16x4 vv = *(const h16x4*)(vpb + (size_t)r*DV);
          cacc.x += a*(float)vv[0]; cacc.y += a*(float)vv[1];
          cacc.z += a*(float)vv[2]; cacc.w += a*(float)vv[3];
        }
      } else {
        const float* vpb = (const float*)P.vals + (size_t)n*TE*DV + l*4;
        for (int r = w; r < L; r += 8){
          float a = e_s[r];
          float4 vv4 = *(const float4*)(vpb + (size_t)r*DV);
          cacc.x += a*vv4.x; cacc.y += a*vv4.y; cacc.z += a*vv4.z; cacc.w += a*vv4.w;
        }
      }
      *(float4*)&ctxp[w][l*4] = cacc;
      __syncthreads();
      if (tid < DV){
        float cv = 0.f;
        #pragma unroll
        for (int q=0;q<8;++q) cv += ctxp[q][tid];
        ctx_s[tid] = cv;
        P.ctx[(size_t)n*DV + tid] = cv;
      }
      __syncthreads();
      #pragma unroll
      for (int vb2=0; vb2<2; ++vb2){
        int vvv = vb2*32 + (tid>>4);
        if (vvv < NV){
          int kbase = (tid&15)*32;
          float s = 0.f;
          #pragma unroll
          for (int q=0;q<32;q+=4){
            float4 w4 = *(const float4*)(P.Wout + (size_t)vvv*512 + kbase + q);
            int k = kbase + q;
            const float* xsv = (k < DK)? &h2s[k] : &ctx_s[k-DK];
            s += w4.x*xsv[0] + w4.y*xsv[1] + w4.z*xsv[2] + w4.w*xsv[3];
          }
          s += __shfl_xor(s,1); s += __shfl_xor(s,2); s += __shfl_xor(s,4); s += __shfl_xor(s,8);
          if ((tid&15)==0) P.out[((size_t)n*STEPS + t)*NV + vvv] = s + P.bout[vvv];
        }
      }
    }
    ++round; ibar(round);
  }
}

// ---------------- host ----------------
extern "C" void kernel_launch(void* const* d_in, const int* in_sizes, int n_in,
                              void* d_out, int out_size, void* d_ws, size_t ws_size,
                              hipStream_t stream)
{
  const float* enc_key = (const float*)d_in[0];
  const float* enc_val = (const float*)d_in[1];
  const int*   text    = (const int*)d_in[2];
  const int*   lens    = (const int*)d_in[3];
  const float* emb     = (const float*)d_in[5];
  const float* W_ih1   = (const float*)d_in[6];
  const float* W_hh1   = (const float*)d_in[7];
  const float* b_ih1   = (const float*)d_in[8];
  const float* b_hh1   = (const float*)d_in[9];
  const float* W_ih2   = (const float*)d_in[10];
  const float* W_hh2   = (const float*)d_in[11];
  const float* b_ih2   = (const float*)d_in[12];
  const float* b_hh2   = (const float*)d_in[13];
  const float* W_out   = (const float*)d_in[14];
  const float* b_out   = (const float*)d_in[15];
  float* out = (float*)d_out;

  char* ws = (char*)d_ws;
  size_t off = 0;
  auto alloc = [&](size_t bytes)->char*{
    char* p = ws + off; off = (off + bytes + 255) & ~(size_t)255; return p;
  };

  u16* Wc1h = (u16*)alloc((size_t)2048*K1*2);
  u16* Wc1l = (u16*)alloc((size_t)2048*K1*2);
  u16* Wc2h = (u16*)alloc((size_t)1024*K2*2);
  u16* Wc2l = (u16*)alloc((size_t)1024*K2*2);
  float* h1b = (float*)alloc((size_t)2*NB*HH*4);
  float* h2b = (float*)alloc((size_t)2*NB*DK*4);
  float* ctx = (float*)alloc((size_t)NB*DV*4);
  unsigned* bar = (unsigned*)alloc(8*256);
  unsigned* reg = (unsigned*)alloc(8*256);

  // zero recurrent state + barrier/registration counters (re-runs each replay)
  size_t zbytes = ((char*)reg + 8*256) - (char*)h1b;
  (void)hipMemsetAsync(h1b, 0, zbytes, stream);

  // f16 K/V copies if workspace allows (R16-proven: absmax 0.0156)
  const size_t encElems = (size_t)NB*TE*DK;
  u16 *keyh = nullptr, *valh = nullptr;
  bool f16kv = (ws_size - off) >= (encElems*2*2 + 1024);
  if (f16kv){
    keyh = (u16*)alloc(encElems*2);
    valh = (u16*)alloc(encElems*2);
    int n8 = (int)(encElems/8);
    conv_f16<<<(n8+255)/256, 256, 0, stream>>>(keyh, enc_key, n8);
    conv_f16<<<(n8+255)/256, 256, 0, stream>>>(valh, enc_val, n8);
  }

  {
    int t8 = 2048*K1/8;
    conv_cat_split<<<(t8+255)/256, 256, 0, stream>>>(Wc1h, Wc1l, W_ih1, W_hh1, 768, 512, t8);
  }
  {
    int t8 = 1024*K2/8;
    conv_cat_split<<<(t8+255)/256, 256, 0, stream>>>(Wc2h, Wc2l, W_ih2, W_hh2, 512, 256, t8);
  }

  Params p;
  p.keys = f16kv ? (const void*)keyh : (const void*)enc_key;
  p.vals = f16kv ? (const void*)valh : (const void*)enc_val;
  p.text = text; p.lens = lens; p.emb = emb;
  p.W1h = Wc1h; p.W1l = Wc1l; p.W2h = Wc2h; p.W2l = Wc2l;
  p.bi1 = b_ih1; p.bh1 = b_hh1; p.bi2 = b_ih2; p.bh2 = b_hh2;
  p.Wout = W_out; p.bout = b_out;
  p.h1b = h1b; p.h2b = h2b; p.ctx = ctx; p.out = out;
  p.bar = bar; p.reg = reg;

  void* kargs[] = { &p };
  // dynamic LDS pushes per-block LDS > 80KB -> exactly 1 block/CU -> exactly
  // 32 blocks per XCD (256 CUs, 32/XCD). Cooperative launch guarantees
  // co-residency of all 256 blocks.
  if (f16kv)
    (void)hipLaunchCooperativeKernel((void*)decoder_k<true>,  dim3(256), dim3(512), kargs, 56*1024, stream);
  else
    (void)hipLaunchCooperativeKernel((void*)decoder_k<false>, dim3(256), dim3(512), kargs, 56*1024, stream);
}

// Round 18
// 22919.131 us; speedup vs baseline: 1.0417x; 1.0417x over previous
//
#include <hip/hip_runtime.h>

typedef unsigned short u16;
typedef unsigned long long u64;
typedef __attribute__((ext_vector_type(8))) short short8;
typedef __attribute__((ext_vector_type(4))) float f32x4;
typedef __attribute__((ext_vector_type(8))) _Float16 h16x8;
typedef __attribute__((ext_vector_type(4))) _Float16 h16x4;

#define NB 256      // batch
#define TE 512      // encoder T
#define DK 256      // key dim
#define DV 256      // value dim
#define HH 512      // hidden
#define NV 35       // vocab
#define STEPS 300
#define TLEN 301
#define K1 1280     // LSTM1 inner dim: emb(512) + ctx(256) + h1(512)
#define K2 768      // LSTM2 inner dim: h1(512) + h2(256)

__device__ __forceinline__ float bf2f(u16 u){ return __uint_as_float(((unsigned)u)<<16); }
__device__ __forceinline__ u16 f2bf(float f){
  unsigned u = __float_as_uint(f);
  u += 0x7fffu + ((u>>16)&1u);   // RNE
  return (u16)(u>>16);
}
__device__ __forceinline__ void splitbf(float f, short& hi, short& lo){
  u16 h = f2bf(f);
  float r = f - bf2f(h);
  hi = (short)h; lo = (short)f2bf(r);
}
__device__ __forceinline__ float sigm(float x){ return 1.f/(1.f+expf(-x)); }

// Coherent 8-float load: 4x relaxed agent-scope u64 atomic loads. Compiles to
// global_load_dwordx2 sc0 (L1 bypass, XCD-L2 is the coherence point) with
// COMPILER-scheduled waitcnt -> pipelined, unlike R17's per-load vmcnt(0).
__device__ __forceinline__ void ld8c(const float* p, float* xs){
  #pragma unroll
  for (int q=0;q<4;++q){
    u64 u = __hip_atomic_load((const u64*)(p + q*2), __ATOMIC_RELAXED, __HIP_MEMORY_SCOPE_AGENT);
    xs[q*2]   = __uint_as_float((unsigned)u);
    xs[q*2+1] = __uint_as_float((unsigned)(u>>32));
  }
}

// ---------------- conversion kernels (once per launch) ----------------
__global__ void conv_cat_split(u16* __restrict__ dhi, u16* __restrict__ dlo,
                               const float* __restrict__ s1, const float* __restrict__ s2,
                               int k1, int k2, int total8){
  int i = blockIdx.x*blockDim.x + threadIdx.x;
  if (i >= total8) return;
  int ktot = k1 + k2;
  long e = (long)i*8;
  int r = (int)(e / ktot); int k = (int)(e - (long)r*ktot);
  const float* s = (k < k1) ? (s1 + (size_t)r*k1 + k) : (s2 + (size_t)r*k2 + (k-k1));
  short8 oh, ol;
  #pragma unroll
  for (int q=0;q<8;++q){ short h,l; splitbf(s[q],h,l); oh[q]=h; ol[q]=l; }
  *(short8*)(dhi + e) = oh;
  *(short8*)(dlo + e) = ol;
}

__global__ void conv_f16(u16* __restrict__ dst, const float* __restrict__ src, int n8){
  int i = blockIdx.x*blockDim.x + threadIdx.x;
  if (i >= n8) return;
  const float* s = src + (size_t)i*8;
  h16x8 o;
  #pragma unroll
  for (int q=0;q<8;++q) o[q] = (_Float16)s[q];
  *(h16x8*)(dst + (size_t)i*8) = o;
}

__device__ __forceinline__ void split8r(const float* x, short8& vh, short8& vl){
  #pragma unroll
  for (int q=0;q<8;++q){ short h,l; splitbf(x[q],h,l); vh[q]=h; vl[q]=l; }
}

struct Params {
  const void *keys, *vals;       // f16 copies (or f32 originals)
  const int *text, *lens;
  const float *emb;
  const u16 *W1h, *W1l, *W2h, *W2l;
  const float *bi1, *bh1, *bi2, *bh2;
  const float *Wout, *bout;
  float *h1b, *h2b, *ctx, *out;
  unsigned *bar;                  // island barrier lines (8 x 256B)
  unsigned *reg;                  // island registration counters (8 x 256B)
};

// ============ XCD-island persistent kernel v2: all 300 steps ============
// 256 blocks x 512 thr, 1 block/CU (forced by ~100KB LDS) -> exactly 32
// blocks per physical XCD (pigeonhole). Island = 32 blocks owning batch rows
// [32*xcd, 32*xcd+32). All sync island-local; cross-block data read via
// sc0 (atomic relaxed) loads; NO fences, NO L2 invalidation, ever.
template<bool F16>
__global__ __launch_bounds__(512) void decoder_k(Params P)
{
  __shared__ __align__(16) float accS[4][4][2][64][4];   // 32KB GEMM reduce
  __shared__ float h2s[DK];
  __shared__ float e_s[TE];
  __shared__ float ctx_s[DV];
  __shared__ float ctxp[8][DV];
  __shared__ float red_s[16];
  __shared__ int islS[2];

  const int tid = threadIdx.x;
  // -------- island registration (physical XCD id + slot) — R17-proven --------
  if (tid == 0){
    unsigned xcd = __builtin_amdgcn_s_getreg(20 | (0<<6) | ((8-1)<<11)) & 7u;  // HW_REG_XCC_ID
    unsigned slot = __hip_atomic_fetch_add(P.reg + xcd*64, 1u,
                      __ATOMIC_RELAXED, __HIP_MEMORY_SCOPE_AGENT);
    islS[0] = (int)xcd; islS[1] = (int)slot;
  }
  __syncthreads();
  const int isl = islS[0], slot = islS[1];     // isl 0..7, slot 0..31
  const int n0 = isl*32;
  unsigned* barL = P.bar + isl*64;             // 4 sub-counters at +0,+16,+32,+48

  const int w = tid>>6, l = tid&63;
  const int nh = w&1, kq = w>>1;               // wave role: n-half, K-quarter
  const int col = l&15, kc = l>>4, ofs = kc*8;
  const int en = tid>>4, ej = tid&15;          // epilogue cell
  const int nhe = en>>4, er = en&15;
  const int lane_e = ((er>>2)<<4) | ej, reg_e = er&3;

  const int jh0_1 = slot*16;                   // lstm1: 32 jh-tiles (512 cols)
  const bool p2act = slot < 16;                // lstm2: 16 jh-tiles (256 cols)
  const int jh0_2 = slot*16;

  float b1i = P.bi1[jh0_1+ej]      + P.bh1[jh0_1+ej];
  float b1f = P.bi1[HH+jh0_1+ej]   + P.bh1[HH+jh0_1+ej];
  float b1g = P.bi1[2*HH+jh0_1+ej] + P.bh1[2*HH+jh0_1+ej];
  float b1o = P.bi1[3*HH+jh0_1+ej] + P.bh1[3*HH+jh0_1+ej];
  float b2i=0.f,b2f=0.f,b2g=0.f,b2o=0.f;
  if (p2act){
    b2i = P.bi2[jh0_2+ej]      + P.bh2[jh0_2+ej];
    b2f = P.bi2[DK+jh0_2+ej]   + P.bh2[DK+jh0_2+ej];
    b2g = P.bi2[2*DK+jh0_2+ej] + P.bh2[2*DK+jh0_2+ej];
    b2o = P.bi2[3*DK+jh0_2+ej] + P.bh2[3*DK+jh0_2+ej];
  }
  const int kb1 = kq*(K1/4), kb2 = kq*(K2/4);
  const u16 *pB1h[4], *pB1l[4], *pB2h[4], *pB2l[4];
  #pragma unroll
  for (int g=0; g<4; ++g){
    size_t r1 = (size_t)(g*512 + jh0_1 + col)*K1 + kb1 + ofs;
    pB1h[g] = P.W1h + r1; pB1l[g] = P.W1l + r1;
    size_t r2 = (size_t)(g*256 + jh0_2 + col)*K2 + kb2 + ofs;
    pB2h[g] = P.W2h + r2; pB2l[g] = P.W2l + r2;
  }

  float c1r = 0.f, c2r = 0.f;                  // register cell state
  unsigned round = 0;

  // island barrier (R17-proven): 4 sub-counters x 8 arrivals; relaxed polls.
  auto ibar = [&](unsigned rnd){
    __syncthreads();                            // drains all waves' stores
    if (threadIdx.x == 0){
      __hip_atomic_fetch_add(barL + (slot>>3)*16, 1u,
                             __ATOMIC_RELAXED, __HIP_MEMORY_SCOPE_AGENT);
      #pragma unroll
      for (int q=0;q<4;++q){
        while (__hip_atomic_load(barL + q*16,
                 __ATOMIC_RELAXED, __HIP_MEMORY_SCOPE_AGENT) < 8u*rnd)
          __builtin_amdgcn_s_sleep(1);
      }
    }
    __syncthreads();
  };

  for (int t=0; t<STEPS; ++t){
    const int par = t&1;
    const float* h1_old = P.h1b + (size_t)par*NB*HH;
    float*       h1_new = P.h1b + (size_t)(par^1)*NB*HH;
    const float* h2_old = P.h2b + (size_t)par*NB*DK;
    float*       h2_new = P.h2b + (size_t)(par^1)*NB*DK;

    // ===== phase 1: LSTM1 — R12 K-split body, coherent ctx/h1 loads =====
    {
      int arow = n0 + nh*16 + col;
      const float* aemb = P.emb + (size_t)P.text[arow*TLEN + t]*HH;
      const float* actx = P.ctx + (size_t)arow*DV;
      const float* ah1  = h1_old + (size_t)arow*HH;

      f32x4 acc[4];
      #pragma unroll
      for (int g=0;g<4;++g) acc[g] = (f32x4){0.f,0.f,0.f,0.f};

      float xs[8]; short8 rbh[4], rbl[4];
      {
        int k = kb1;   // chunk base; 32-chunks never straddle region bounds
        if (k < 512){
          *(float4*)&xs[0] = *(const float4*)(aemb + k + ofs);
          *(float4*)&xs[4] = *(const float4*)(aemb + k + ofs + 4);
        } else if (k < 768) ld8c(actx + (k-512) + ofs, xs);
        else                ld8c(ah1 + (k-768) + ofs, xs);
        #pragma unroll
        for (int g=0;g<4;++g){ rbh[g] = *(const short8*)(pB1h[g]); rbl[g] = *(const short8*)(pB1l[g]); }
      }
      for (int k0=0; k0<K1/4; k0+=32){
        float cxs[8];
        #pragma unroll
        for (int q=0;q<8;++q) cxs[q] = xs[q];
        short8 cbh[4], cbl[4];
        #pragma unroll
        for (int g=0;g<4;++g){ cbh[g]=rbh[g]; cbl[g]=rbl[g]; }
        int k0n = k0 + 32;
        if (k0n < K1/4){
          int k = kb1 + k0n;
          if (k < 512){
            *(float4*)&xs[0] = *(const float4*)(aemb + k + ofs);
            *(float4*)&xs[4] = *(const float4*)(aemb + k + ofs + 4);
          } else if (k < 768) ld8c(actx + (k-512) + ofs, xs);
          else                ld8c(ah1 + (k-768) + ofs, xs);
          #pragma unroll
          for (int g=0;g<4;++g){ rbh[g] = *(const short8*)(pB1h[g] + k0n); rbl[g] = *(const short8*)(pB1l[g] + k0n); }
        }
        short8 avh, avl;
        split8r(cxs, avh, avl);
        #pragma unroll
        for (int g=0; g<4; ++g){
          acc[g] = __builtin_amdgcn_mfma_f32_16x16x32_bf16(avh, cbh[g], acc[g], 0,0,0);
          acc[g] = __builtin_amdgcn_mfma_f32_16x16x32_bf16(avl, cbh[g], acc[g], 0,0,0);
          acc[g] = __builtin_amdgcn_mfma_f32_16x16x32_bf16(avh, cbl[g], acc[g], 0,0,0);
        }
      }
      #pragma unroll
      for (int g=0;g<4;++g) *(f32x4*)&accS[g][kq][nh][l][0] = acc[g];
      __syncthreads();
      {
        float gv4[4];
        #pragma unroll
        for (int g=0;g<4;++g){
          gv4[g] = accS[g][0][nhe][lane_e][reg_e] + accS[g][1][nhe][lane_e][reg_e]
                 + accS[g][2][nhe][lane_e][reg_e] + accS[g][3][nhe][lane_e][reg_e];
        }
        float iv = sigm(gv4[0]+b1i);
        float fv = sigm(gv4[1]+b1f);
        float gg = tanhf(gv4[2]+b1g);
        float ov = sigm(gv4[3]+b1o);
        float cn = fv*c1r + iv*gg;
        c1r = cn;
        h1_new[(size_t)(n0+en)*HH + jh0_1+ej] = ov*tanhf(cn);
      }
    }
    ++round; ibar(round);

    // ===== phase 2: LSTM2 — R12 K-split body (slots 0..15), coherent loads =====
    if (p2act){
      int arow = n0 + nh*16 + col;
      const float* ah1 = h1_new + (size_t)arow*HH;
      const float* ah2 = h2_old + (size_t)arow*DK;

      f32x4 acc[4];
      #pragma unroll
      for (int g=0;g<4;++g) acc[g] = (f32x4){0.f,0.f,0.f,0.f};

      float xs[8]; short8 rbh[4], rbl[4];
      {
        int k = kb2;
        if (k < 512) ld8c(ah1 + k + ofs, xs);
        else         ld8c(ah2 + (k-512) + ofs, xs);
        #pragma unroll
        for (int g=0;g<4;++g){ rbh[g] = *(const short8*)(pB2h[g]); rbl[g] = *(const short8*)(pB2l[g]); }
      }
      for (int k0=0; k0<K2/4; k0+=32){
        float cxs[8];
        #pragma unroll
        for (int q=0;q<8;++q) cxs[q] = xs[q];
        short8 cbh[4], cbl[4];
        #pragma unroll
        for (int g=0;g<4;++g){ cbh[g]=rbh[g]; cbl[g]=rbl[g]; }
        int k0n = k0 + 32;
        if (k0n < K2/4){
          int k = kb2 + k0n;
          if (k < 512) ld8c(ah1 + k + ofs, xs);
          else         ld8c(ah2 + (k-512) + ofs, xs);
          #pragma unroll
          for (int g=0;g<4;++g){ rbh[g] = *(const short8*)(pB2h[g] + k0n); rbl[g] = *(const short8*)(pB2l[g] + k0n); }
        }
        short8 avh, avl;
        split8r(cxs, avh, avl);
        #pragma unroll
        for (int g=0; g<4; ++g){
          acc[g] = __builtin_amdgcn_mfma_f32_16x16x32_bf16(avh, cbh[g], acc[g], 0,0,0);
          acc[g] = __builtin_amdgcn_mfma_f32_16x16x32_bf16(avl, cbh[g], acc[g], 0,0,0);
          acc[g] = __builtin_amdgcn_mfma_f32_16x16x32_bf16(avh, cbl[g], acc[g], 0,0,0);
        }
      }
      #pragma unroll
      for (int g=0;g<4;++g) *(f32x4*)&accS[g][kq][nh][l][0] = acc[g];
      __syncthreads();
      {
        float gv4[4];
        #pragma unroll
        for (int g=0;g<4;++g){
          gv4[g] = accS[g][0][nhe][lane_e][reg_e] + accS[g][1][nhe][lane_e][reg_e]
                 + accS[g][2][nhe][lane_e][reg_e] + accS[g][3][nhe][lane_e][reg_e];
        }
        float iv = sigm(gv4[0]+b2i);
        float fv = sigm(gv4[1]+b2f);
        float gg = tanhf(gv4[2]+b2g);
        float ov = sigm(gv4[3]+b2o);
        float cn = fv*c2r + iv*gg;
        c2r = cn;
        h2_new[(size_t)(n0+en)*DK + jh0_2+ej] = ov*tanhf(cn);
      }
    }
    ++round; ibar(round);

    // ===== phase 3: attention + output (row n = n0 + slot) =====
    {
      const int n = n0 + slot;
      int L = P.lens[n] >> 3;
      if (tid < 128){
        u64 u = __hip_atomic_load((const u64*)(h2_new + (size_t)n*DK + tid*2),
                                  __ATOMIC_RELAXED, __HIP_MEMORY_SCOPE_AGENT);
        h2s[tid*2]   = __uint_as_float((unsigned)u);
        h2s[tid*2+1] = __uint_as_float((unsigned)(u>>32));
      }
      __syncthreads();
      float qreg[32];
      {
        int off = (l&7)*32;
        #pragma unroll
        for (int q=0;q<32;q+=4){
          float4 v4 = *(const float4*)&h2s[off+q];
          qreg[q]=v4.x; qreg[q+1]=v4.y; qreg[q+2]=v4.z; qreg[q+3]=v4.w;
        }
      }
      for (int r = w*8 + (l>>3); r < L; r += 64){
        float s = 0.f;
        if (F16){
          const u16* kr = (const u16*)P.keys + (size_t)(n*TE + r)*DK + (l&7)*32;
          #pragma unroll
          for (int q=0;q<32;q+=8){
            h16x8 kv = *(const h16x8*)(kr + q);
            s += (float)kv[0]*qreg[q+0] + (float)kv[1]*qreg[q+1]
               + (float)kv[2]*qreg[q+2] + (float)kv[3]*qreg[q+3]
               + (float)kv[4]*qreg[q+4] + (float)kv[5]*qreg[q+5]
               + (float)kv[6]*qreg[q+6] + (float)kv[7]*qreg[q+7];
          }
        } else {
          const float* kr = (const float*)P.keys + (size_t)(n*TE + r)*DK + (l&7)*32;
          #pragma unroll
          for (int q=0;q<32;q+=4){
            float4 kv = *(const float4*)(kr + q);
            s += kv.x*qreg[q] + kv.y*qreg[q+1] + kv.z*qreg[q+2] + kv.w*qreg[q+3];
          }
        }
        s += __shfl_xor(s,1); s += __shfl_xor(s,2); s += __shfl_xor(s,4);
        if ((l&7)==0) e_s[r] = s;
      }
      __syncthreads();
      float v = (tid < L) ? e_s[tid] : -1e30f;
      float m = v;
      #pragma unroll
      for (int o=1;o<64;o<<=1) m = fmaxf(m, __shfl_xor(m,o));
      if (l==0) red_s[w] = m;
      __syncthreads();
      m = red_s[0];
      #pragma unroll
      for (int q=1;q<8;++q) m = fmaxf(m, red_s[q]);
      float p = (tid < L) ? expf(v-m) : 0.f;
      float sm = p;
      #pragma unroll
      for (int o=1;o<64;o<<=1) sm += __shfl_xor(sm,o);
      if (l==0) red_s[8+w] = sm;
      __syncthreads();
      sm = red_s[8];
      #pragma unroll
      for (int q=1;q<8;++q) sm += red_s[8+q];
      e_s[tid] = p * (1.f/sm);
      __syncthreads();
      float4 cacc = {0.f,0.f,0.f,0.f};
      if (F16){
        const u16* vpb = (const u16*)P.vals + (size_t)n*TE*DV + l*4;
        for (int r = w; r < L; r += 8){
          float a = e_s[r];
          h16x4 vv = *(const h16x4*)(vpb + (size_t)r*DV);
          cacc.x += a*(float)vv[0]; cacc.y += a*(float)vv[1];
          cacc.z += a*(float)vv[2]; cacc.w += a*(float)vv[3];
        }
      } else {
        const float* vpb = (const float*)P.vals + (size_t)n*TE*DV + l*4;
        for (int r = w; r < L; r += 8){
          float a = e_s[r];
          float4 vv4 = *(const float4*)(vpb + (size_t)r*DV);
          cacc.x += a*vv4.x; cacc.y += a*vv4.y; cacc.z += a*vv4.z; cacc.w += a*vv4.w;
        }
      }
      *(float4*)&ctxp[w][l*4] = cacc;
      __syncthreads();
      if (tid < DV){
        float cv = 0.f;
        #pragma unroll
        for (int q=0;q<8;++q) cv += ctxp[q][tid];
        ctx_s[tid] = cv;
        P.ctx[(size_t)n*DV + tid] = cv;
      }
      __syncthreads();
      #pragma unroll
      for (int vb2=0; vb2<2; ++vb2){
        int vvv = vb2*32 + (tid>>4);
        if (vvv < NV){
          int kbase = (tid&15)*32;
          float s = 0.f;
          #pragma unroll
          for (int q=0;q<32;q+=4){
            float4 w4 = *(const float4*)(P.Wout + (size_t)vvv*512 + kbase + q);
            int k = kbase + q;
            const float* xsv = (k < DK)? &h2s[k] : &ctx_s[k-DK];
            s += w4.x*xsv[0] + w4.y*xsv[1] + w4.z*xsv[2] + w4.w*xsv[3];
          }
          s += __shfl_xor(s,1); s += __shfl_xor(s,2); s += __shfl_xor(s,4); s += __shfl_xor(s,8);
          if ((tid&15)==0) P.out[((size_t)n*STEPS + t)*NV + vvv] = s + P.bout[vvv];
        }
      }
    }
    ++round; ibar(round);
  }
}

// ---------------- host ----------------
extern "C" void kernel_launch(void* const* d_in, const int* in_sizes, int n_in,
                              void* d_out, int out_size, void* d_ws, size_t ws_size,
                              hipStream_t stream)
{
  const float* enc_key = (const float*)d_in[0];
  const float* enc_val = (const float*)d_in[1];
  const int*   text    = (const int*)d_in[2];
  const int*   lens    = (const int*)d_in[3];
  const float* emb     = (const float*)d_in[5];
  const float* W_ih1   = (const float*)d_in[6];
  const float* W_hh1   = (const float*)d_in[7];
  const float* b_ih1   = (const float*)d_in[8];
  const float* b_hh1   = (const float*)d_in[9];
  const float* W_ih2   = (const float*)d_in[10];
  const float* W_hh2   = (const float*)d_in[11];
  const float* b_ih2   = (const float*)d_in[12];
  const float* b_hh2   = (const float*)d_in[13];
  const float* W_out   = (const float*)d_in[14];
  const float* b_out   = (const float*)d_in[15];
  float* out = (float*)d_out;

  char* ws = (char*)d_ws;
  size_t off = 0;
  auto alloc = [&](size_t bytes)->char*{
    char* p = ws + off; off = (off + bytes + 255) & ~(size_t)255; return p;
  };

  u16* Wc1h = (u16*)alloc((size_t)2048*K1*2);
  u16* Wc1l = (u16*)alloc((size_t)2048*K1*2);
  u16* Wc2h = (u16*)alloc((size_t)1024*K2*2);
  u16* Wc2l = (u16*)alloc((size_t)1024*K2*2);
  float* h1b = (float*)alloc((size_t)2*NB*HH*4);
  float* h2b = (float*)alloc((size_t)2*NB*DK*4);
  float* ctx = (float*)alloc((size_t)NB*DV*4);
  unsigned* bar = (unsigned*)alloc(8*256);
  unsigned* reg = (unsigned*)alloc(8*256);

  // zero recurrent state + barrier/registration counters (re-runs each replay)
  size_t zbytes = ((char*)reg + 8*256) - (char*)h1b;
  (void)hipMemsetAsync(h1b, 0, zbytes, stream);

  // f16 K/V copies if workspace allows (R16-proven: absmax 0.0156)
  const size_t encElems = (size_t)NB*TE*DK;
  u16 *keyh = nullptr, *valh = nullptr;
  bool f16kv = (ws_size - off) >= (encElems*2*2 + 1024);
  if (f16kv){
    keyh = (u16*)alloc(encElems*2);
    valh = (u16*)alloc(encElems*2);
    int n8 = (int)(encElems/8);
    conv_f16<<<(n8+255)/256, 256, 0, stream>>>(keyh, enc_key, n8);
    conv_f16<<<(n8+255)/256, 256, 0, stream>>>(valh, enc_val, n8);
  }

  {
    int t8 = 2048*K1/8;
    conv_cat_split<<<(t8+255)/256, 256, 0, stream>>>(Wc1h, Wc1l, W_ih1, W_hh1, 768, 512, t8);
  }
  {
    int t8 = 1024*K2/8;
    conv_cat_split<<<(t8+255)/256, 256, 0, stream>>>(Wc2h, Wc2l, W_ih2, W_hh2, 512, 256, t8);
  }

  Params p;
  p.keys = f16kv ? (const void*)keyh : (const void*)enc_key;
  p.vals = f16kv ? (const void*)valh : (const void*)enc_val;
  p.text = text; p.lens = lens; p.emb = emb;
  p.W1h = Wc1h; p.W1l = Wc1l; p.W2h = Wc2h; p.W2l = Wc2l;
  p.bi1 = b_ih1; p.bh1 = b_hh1; p.bi2 = b_ih2; p.bh2 = b_hh2;
  p.Wout = W_out; p.bout = b_out;
  p.h1b = h1b; p.h2b = h2b; p.ctx = ctx; p.out = out;
  p.bar = bar; p.reg = reg;

  void* kargs[] = { &p };
  // ~45KB static + 56KB dynamic LDS -> 1 block/CU -> exactly 32 blocks/XCD.
  if (f16kv)
    (void)hipLaunchCooperativeKernel((void*)decoder_k<true>,  dim3(256), dim3(512), kargs, 56*1024, stream);
  else
    (void)hipLaunchCooperativeKernel((void*)decoder_k<false>, dim3(256), dim3(512), kargs, 56*1024, stream);
}

// Round 19
// 19195.154 us; speedup vs baseline: 1.2437x; 1.1940x over previous
//
#include <hip/hip_runtime.h>

typedef unsigned short u16;
typedef __attribute__((ext_vector_type(8))) short short8;
typedef __attribute__((ext_vector_type(4))) float f32x4;
typedef __attribute__((ext_vector_type(8))) _Float16 h16x8;
typedef __attribute__((ext_vector_type(4))) _Float16 h16x4;

#define NB 256      // batch
#define TE 512      // encoder T
#define DK 256      // key dim
#define DV 256      // value dim
#define HH 512      // hidden
#define NV 35       // vocab
#define STEPS 300
#define TLEN 301
#define K1 1280     // LSTM1 inner dim: emb(512) + ctx(256) + h1(512)
#define K2 768      // LSTM2 inner dim: h1(512) + h2(256)

__device__ __forceinline__ float bf2f(u16 u){ return __uint_as_float(((unsigned)u)<<16); }
__device__ __forceinline__ u16 f2bf(float f){
  unsigned u = __float_as_uint(f);
  u += 0x7fffu + ((u>>16)&1u);   // RNE
  return (u16)(u>>16);
}
__device__ __forceinline__ void splitbf(float f, short& hi, short& lo){
  u16 h = f2bf(f);
  float r = f - bf2f(h);
  hi = (short)h; lo = (short)f2bf(r);
}
__device__ __forceinline__ float sigm(float x){ return 1.f/(1.f+expf(-x)); }

// ---------------- conversion kernels (once per launch) ----------------
__global__ void conv_cat_split(u16* __restrict__ dhi, u16* __restrict__ dlo,
                               const float* __restrict__ s1, const float* __restrict__ s2,
                               int k1, int k2, int total8){
  int i = blockIdx.x*blockDim.x + threadIdx.x;
  if (i >= total8) return;
  int ktot = k1 + k2;
  long e = (long)i*8;
  int r = (int)(e / ktot); int k = (int)(e - (long)r*ktot);
  const float* s = (k < k1) ? (s1 + (size_t)r*k1 + k) : (s2 + (size_t)r*k2 + (k-k1));
  short8 oh, ol;
  #pragma unroll
  for (int q=0;q<8;++q){ short h,l; splitbf(s[q],h,l); oh[q]=h; ol[q]=l; }
  *(short8*)(dhi + e) = oh;
  *(short8*)(dlo + e) = ol;
}

__global__ void conv_f16(u16* __restrict__ dst, const float* __restrict__ src, int n8){
  int i = blockIdx.x*blockDim.x + threadIdx.x;
  if (i >= n8) return;
  const float* s = src + (size_t)i*8;
  h16x8 o;
  #pragma unroll
  for (int q=0;q<8;++q) o[q] = (_Float16)s[q];
  *(h16x8*)(dst + (size_t)i*8) = o;
}

__device__ __forceinline__ void split8r(const float* x, short8& vh, short8& vl){
  #pragma unroll
  for (int q=0;q<8;++q){ short h,l; splitbf(x[q],h,l); vh[q]=h; vl[q]=l; }
}

// ---------------- LSTM1: K-split 8-wave GEMM + cell update (R12-proven) ----------------
__global__ __launch_bounds__(512) void lstm1_k(
  const int* __restrict__ text, int t, int par,
  const float* __restrict__ emb,
  const float* __restrict__ ctx,
  float* __restrict__ h1b,
  float* __restrict__ c1,
  const u16* __restrict__ Whi, const u16* __restrict__ Wlo,
  const float* __restrict__ b_ih, const float* __restrict__ b_hh)
{
  __shared__ __align__(16) float accS[4][4][2][64][4];   // [gate][kq][nh][lane][reg] 32KB
  const float* h1_old = h1b + (size_t)par*NB*HH;
  float* h1_new = h1b + (size_t)(par^1)*NB*HH;
  int b = blockIdx.x;
  int jt  = (b&7)*4 + ((b>>3)&3);     // XCD swizzle: W slice L2-resident per XCD
  int jh0 = jt*16;
  int n0  = (b>>5)*32;
  int tid = threadIdx.x, w = tid>>6, l = tid&63;
  int nh = w&1, kq = w>>1;
  int kbase = kq*(K1/4);
  int col = l&15, kc = l>>4, ofs = kc*8;

  int arow = n0 + nh*16 + col;
  const float* aemb = emb + (size_t)text[arow*TLEN + t]*HH;
  const float* actx = ctx + (size_t)arow*DV;
  const float* ah1  = h1_old + (size_t)arow*HH;

  const u16* pBh[4]; const u16* pBl[4];
  #pragma unroll
  for (int g=0; g<4; ++g){
    size_t r = (size_t)(g*512 + jh0 + col)*K1 + kbase + ofs;
    pBh[g] = Whi + r; pBl[g] = Wlo + r;
  }

  f32x4 acc[4];
  #pragma unroll
  for (int g=0;g<4;++g) acc[g] = (f32x4){0.f,0.f,0.f,0.f};

  float xs[8]; short8 rbh[4], rbl[4];
  {
    int k = kbase;
    const float* src = (k<512)? (aemb+k) : (k<768)? (actx+(k-512)) : (ah1+(k-768));
    *(float4*)&xs[0] = *(const float4*)(src + ofs);
    *(float4*)&xs[4] = *(const float4*)(src + ofs + 4);
    #pragma unroll
    for (int g=0;g<4;++g){ rbh[g] = *(const short8*)(pBh[g]); rbl[g] = *(const short8*)(pBl[g]); }
  }

  for (int k0=0; k0<K1/4; k0+=32){
    float cxs[8];
    #pragma unroll
    for (int q=0;q<8;++q) cxs[q] = xs[q];
    short8 cbh[4], cbl[4];
    #pragma unroll
    for (int g=0;g<4;++g){ cbh[g]=rbh[g]; cbl[g]=rbl[g]; }
    int k0n = k0 + 32;
    if (k0n < K1/4){
      int k = kbase + k0n;
      const float* src = (k<512)? (aemb+k) : (k<768)? (actx+(k-512)) : (ah1+(k-768));
      *(float4*)&xs[0] = *(const float4*)(src + ofs);
      *(float4*)&xs[4] = *(const float4*)(src + ofs + 4);
      #pragma unroll
      for (int g=0;g<4;++g){ rbh[g] = *(const short8*)(pBh[g] + k0n); rbl[g] = *(const short8*)(pBl[g] + k0n); }
    }
    short8 avh, avl;
    split8r(cxs, avh, avl);
    #pragma unroll
    for (int g=0; g<4; ++g){
      acc[g] = __builtin_amdgcn_mfma_f32_16x16x32_bf16(avh, cbh[g], acc[g], 0,0,0);
      acc[g] = __builtin_amdgcn_mfma_f32_16x16x32_bf16(avl, cbh[g], acc[g], 0,0,0);
      acc[g] = __builtin_amdgcn_mfma_f32_16x16x32_bf16(avh, cbl[g], acc[g], 0,0,0);
    }
  }

  #pragma unroll
  for (int g=0;g<4;++g) *(f32x4*)&accS[g][kq][nh][l][0] = acc[g];
  __syncthreads();

  int en = tid>>4, ej = tid&15;
  int nhe = en>>4, r = en&15;
  int lane_e = ((r>>2)<<4) | ej, reg = r&3;
  float gv4[4];
  #pragma unroll
  for (int g=0;g<4;++g){
    gv4[g] = accS[g][0][nhe][lane_e][reg] + accS[g][1][nhe][lane_e][reg]
           + accS[g][2][nhe][lane_e][reg] + accS[g][3][nhe][lane_e][reg];
  }
  int jh = jh0 + ej;
  float bi  = b_ih[jh]      + b_hh[jh];
  float bff = b_ih[HH+jh]   + b_hh[HH+jh];
  float bg  = b_ih[2*HH+jh] + b_hh[2*HH+jh];
  float bo  = b_ih[3*HH+jh] + b_hh[3*HH+jh];
  size_t idx = (size_t)(n0+en)*HH + jh;
  float iv = sigm(gv4[0]+bi);
  float fv = sigm(gv4[1]+bff);
  float gg = tanhf(gv4[2]+bg);
  float ov = sigm(gv4[3]+bo);
  float cn = fv*c1[idx] + iv*gg;
  c1[idx] = cn;
  h1_new[idx] = ov*tanhf(cn);
}

// ---------------- LSTM2: K-split 8-wave, K=768 (R12-proven) ----------------
__global__ __launch_bounds__(512) void lstm2_k(
  int par,
  const float* __restrict__ h1b,
  float* __restrict__ h2b,
  float* __restrict__ c2,
  const u16* __restrict__ Whi, const u16* __restrict__ Wlo,
  const float* __restrict__ b_ih, const float* __restrict__ b_hh)
{
  __shared__ __align__(16) float accS[4][4][2][64][4];
  const float* h1_cur = h1b + (size_t)(par^1)*NB*HH;
  const float* h2_old = h2b + (size_t)par*NB*DK;
  float* h2_new = h2b + (size_t)(par^1)*NB*DK;
  int b = blockIdx.x;
  int jt  = (b&7)*2 + ((b>>3)&1);
  int jh0 = jt*16;
  int n0  = (b>>4)*32;
  int tid = threadIdx.x, w = tid>>6, l = tid&63;
  int nh = w&1, kq = w>>1;
  int kbase = kq*(K2/4);
  int col = l&15, kc = l>>4, ofs = kc*8;

  int arow = n0 + nh*16 + col;
  const float* ah1 = h1_cur + (size_t)arow*HH;
  const float* ah2 = h2_old + (size_t)arow*DK;

  const u16* pBh[4]; const u16* pBl[4];
  #pragma unroll
  for (int g=0; g<4; ++g){
    size_t r = (size_t)(g*256 + jh0 + col)*K2 + kbase + ofs;
    pBh[g] = Whi + r; pBl[g] = Wlo + r;
  }

  f32x4 acc[4];
  #pragma unroll
  for (int g=0;g<4;++g) acc[g] = (f32x4){0.f,0.f,0.f,0.f};

  float xs[8]; short8 rbh[4], rbl[4];
  {
    int k = kbase;
    const float* src = (k<512)? (ah1+k) : (ah2+(k-512));
    *(float4*)&xs[0] = *(const float4*)(src + ofs);
    *(float4*)&xs[4] = *(const float4*)(src + ofs + 4);
    #pragma unroll
    for (int g=0;g<4;++g){ rbh[g] = *(const short8*)(pBh[g]); rbl[g] = *(const short8*)(pBl[g]); }
  }

  for (int k0=0; k0<K2/4; k0+=32){
    float cxs[8];
    #pragma unroll
    for (int q=0;q<8;++q) cxs[q] = xs[q];
    short8 cbh[4], cbl[4];
    #pragma unroll
    for (int g=0;g<4;++g){ cbh[g]=rbh[g]; cbl[g]=rbl[g]; }
    int k0n = k0 + 32;
    if (k0n < K2/4){
      int k = kbase + k0n;
      const float* src = (k<512)? (ah1+k) : (ah2+(k-512));
      *(float4*)&xs[0] = *(const float4*)(src + ofs);
      *(float4*)&xs[4] = *(const float4*)(src + ofs + 4);
      #pragma unroll
      for (int g=0;g<4;++g){ rbh[g] = *(const short8*)(pBh[g] + k0n); rbl[g] = *(const short8*)(pBl[g] + k0n); }
    }
    short8 avh, avl;
    split8r(cxs, avh, avl);
    #pragma unroll
    for (int g=0; g<4; ++g){
      acc[g] = __builtin_amdgcn_mfma_f32_16x16x32_bf16(avh, cbh[g], acc[g], 0,0,0);
      acc[g] = __builtin_amdgcn_mfma_f32_16x16x32_bf16(avl, cbh[g], acc[g], 0,0,0);
      acc[g] = __builtin_amdgcn_mfma_f32_16x16x32_bf16(avh, cbl[g], acc[g], 0,0,0);
    }
  }

  #pragma unroll
  for (int g=0;g<4;++g) *(f32x4*)&accS[g][kq][nh][l][0] = acc[g];
  __syncthreads();

  int en = tid>>4, ej = tid&15;
  int nhe = en>>4, r = en&15;
  int lane_e = ((r>>2)<<4) | ej, reg = r&3;
  float gv4[4];
  #pragma unroll
  for (int g=0;g<4;++g){
    gv4[g] = accS[g][0][nhe][lane_e][reg] + accS[g][1][nhe][lane_e][reg]
           + accS[g][2][nhe][lane_e][reg] + accS[g][3][nhe][lane_e][reg];
  }
  int jh = jh0 + ej;
  float bi  = b_ih[jh]      + b_hh[jh];
  float bff = b_ih[DK+jh]   + b_hh[DK+jh];
  float bg  = b_ih[2*DK+jh] + b_hh[2*DK+jh];
  float bo  = b_ih[3*DK+jh] + b_hh[3*DK+jh];
  size_t idx = (size_t)(n0+en)*DK + jh;
  float iv = sigm(gv4[0]+bi);
  float fv = sigm(gv4[1]+bff);
  float gg = tanhf(gv4[2]+bg);
  float ov = sigm(gv4[3]+bo);
  float cn = fv*c2[idx] + iv*gg;
  c2[idx] = cn;
  h2_new[idx] = ov*tanhf(cn);
}

// ---------------- attention + softmax + ctx + output projection ----------------
// MLP-unrolled: QK processes 2 rows/iter (8 indep loads/lane), PV 4 rows/iter
// (2KB contiguous in flight per wave). F16 path reads f16 K/V copies.
template<bool F16>
__global__ __launch_bounds__(512) void attn_k(
  const void* __restrict__ keysv, const void* __restrict__ valsv,
  const int* __restrict__ lens,
  const float* __restrict__ h2b, int par,
  float* __restrict__ ctx,
  const float* __restrict__ Wout, const float* __restrict__ b_out,
  float* __restrict__ out, int t)
{
  __shared__ float h2s[DK];
  __shared__ float e_s[TE];
  __shared__ float ctx_s[DV];
  __shared__ float ctxp[8][DV];
  __shared__ float red_s[16];
  int n = blockIdx.x, tid = threadIdx.x;
  int wv = tid>>6, lane = tid&63;
  const float* h2cur = h2b + (size_t)(par^1)*NB*DK;
  int L = lens[n] >> 3;
  if (tid < DK) h2s[tid] = h2cur[n*DK + tid];
  __syncthreads();
  float qreg[32];
  {
    int off = (lane&7)*32;
    #pragma unroll
    for (int q=0;q<32;q+=4){
      float4 v4 = *(const float4*)&h2s[off+q];
      qreg[q]=v4.x; qreg[q+1]=v4.y; qreg[q+2]=v4.z; qreg[q+3]=v4.w;
    }
  }
  // ---- QK: 8 lanes/row, 64 row-slots, unroll 2 rows/iter ----
  {
    int r = wv*8 + (lane>>3);
    int off = (lane&7)*32;
    if (F16){
      const u16* kb = (const u16*)keysv + (size_t)n*TE*DK + off;
      for (; r+64 < L; r += 128){
        const u16* kr0 = kb + (size_t)r*DK;
        const u16* kr1 = kb + (size_t)(r+64)*DK;
        h16x8 k0[4], k1[4];
        #pragma unroll
        for (int q=0;q<4;++q){ k0[q] = *(const h16x8*)(kr0 + q*8); }
        #pragma unroll
        for (int q=0;q<4;++q){ k1[q] = *(const h16x8*)(kr1 + q*8); }
        float s0=0.f, s1=0.f;
        #pragma unroll
        for (int q=0;q<4;++q){
          #pragma unroll
          for (int j=0;j<8;++j){
            s0 += (float)k0[q][j]*qreg[q*8+j];
            s1 += (float)k1[q][j]*qreg[q*8+j];
          }
        }
        s0 += __shfl_xor(s0,1); s0 += __shfl_xor(s0,2); s0 += __shfl_xor(s0,4);
        s1 += __shfl_xor(s1,1); s1 += __shfl_xor(s1,2); s1 += __shfl_xor(s1,4);
        if ((lane&7)==0){ e_s[r] = s0; e_s[r+64] = s1; }
      }
      for (; r < L; r += 64){
        const u16* kr = kb + (size_t)r*DK;
        float s = 0.f;
        #pragma unroll
        for (int q=0;q<4;++q){
          h16x8 kv = *(const h16x8*)(kr + q*8);
          #pragma unroll
          for (int j=0;j<8;++j) s += (float)kv[j]*qreg[q*8+j];
        }
        s += __shfl_xor(s,1); s += __shfl_xor(s,2); s += __shfl_xor(s,4);
        if ((lane&7)==0) e_s[r] = s;
      }
    } else {
      const float* kb = (const float*)keysv + (size_t)n*TE*DK + off;
      for (; r+64 < L; r += 128){
        const float* kr0 = kb + (size_t)r*DK;
        const float* kr1 = kb + (size_t)(r+64)*DK;
        float4 k0[8], k1[8];
        #pragma unroll
        for (int q=0;q<8;++q){ k0[q] = *(const float4*)(kr0 + q*4); }
        #pragma unroll
        for (int q=0;q<8;++q){ k1[q] = *(const float4*)(kr1 + q*4); }
        float s0=0.f, s1=0.f;
        #pragma unroll
        for (int q=0;q<8;++q){
          s0 += k0[q].x*qreg[q*4] + k0[q].y*qreg[q*4+1] + k0[q].z*qreg[q*4+2] + k0[q].w*qreg[q*4+3];
          s1 += k1[q].x*qreg[q*4] + k1[q].y*qreg[q*4+1] + k1[q].z*qreg[q*4+2] + k1[q].w*qreg[q*4+3];
        }
        s0 += __shfl_xor(s0,1); s0 += __shfl_xor(s0,2); s0 += __shfl_xor(s0,4);
        s1 += __shfl_xor(s1,1); s1 += __shfl_xor(s1,2); s1 += __shfl_xor(s1,4);
        if ((lane&7)==0){ e_s[r] = s0; e_s[r+64] = s1; }
      }
      for (; r < L; r += 64){
        const float* kr = kb + (size_t)r*DK;
        float s = 0.f;
        #pragma unroll
        for (int q=0;q<8;++q){
          float4 kv = *(const float4*)(kr + q*4);
          s += kv.x*qreg[q*4] + kv.y*qreg[q*4+1] + kv.z*qreg[q*4+2] + kv.w*qreg[q*4+3];
        }
        s += __shfl_xor(s,1); s += __shfl_xor(s,2); s += __shfl_xor(s,4);
        if ((lane&7)==0) e_s[r] = s;
      }
    }
  }
  __syncthreads();
  float v = (tid < L) ? e_s[tid] : -1e30f;
  float m = v;
  #pragma unroll
  for (int o=1;o<64;o<<=1) m = fmaxf(m, __shfl_xor(m,o));
  if (lane==0) red_s[wv] = m;
  __syncthreads();
  m = red_s[0];
  #pragma unroll
  for (int q=1;q<8;++q) m = fmaxf(m, red_s[q]);
  float p = (tid < L) ? expf(v-m) : 0.f;
  float sm = p;
  #pragma unroll
  for (int o=1;o<64;o<<=1) sm += __shfl_xor(sm,o);
  if (lane==0) red_s[8+wv] = sm;
  __syncthreads();
  sm = red_s[8];
  #pragma unroll
  for (int q=1;q<8;++q) sm += red_s[8+q];
  e_s[tid] = p * (1.f/sm);
  __syncthreads();
  // ---- PV: wave-strided rows, unroll 4 rows/iter ----
  float4 cacc = {0.f,0.f,0.f,0.f};
  {
    int r = wv;
    if (F16){
      const u16* vpb = (const u16*)valsv + (size_t)n*TE*DV + lane*4;
      for (; r+24 < L; r += 32){
        float a0=e_s[r], a1=e_s[r+8], a2=e_s[r+16], a3=e_s[r+24];
        h16x4 v0 = *(const h16x4*)(vpb + (size_t)r*DV);
        h16x4 v1 = *(const h16x4*)(vpb + (size_t)(r+8)*DV);
        h16x4 v2 = *(const h16x4*)(vpb + (size_t)(r+16)*DV);
        h16x4 v3 = *(const h16x4*)(vpb + (size_t)(r+24)*DV);
        cacc.x += a0*(float)v0[0] + a1*(float)v1[0] + a2*(float)v2[0] + a3*(float)v3[0];
        cacc.y += a0*(float)v0[1] + a1*(float)v1[1] + a2*(float)v2[1] + a3*(float)v3[1];
        cacc.z += a0*(float)v0[2] + a1*(float)v1[2] + a2*(float)v2[2] + a3*(float)v3[2];
        cacc.w += a0*(float)v0[3] + a1*(float)v1[3] + a2*(float)v2[3] + a3*(float)v3[3];
      }
      for (; r < L; r += 8){
        float a = e_s[r];
        h16x4 vv = *(const h16x4*)(vpb + (size_t)r*DV);
        cacc.x += a*(float)vv[0]; cacc.y += a*(float)vv[1];
        cacc.z += a*(float)vv[2]; cacc.w += a*(float)vv[3];
      }
    } else {
      const float* vpb = (const float*)valsv + (size_t)n*TE*DV + lane*4;
      for (; r+24 < L; r += 32){
        float a0=e_s[r], a1=e_s[r+8], a2=e_s[r+16], a3=e_s[r+24];
        float4 v0 = *(const float4*)(vpb + (size_t)r*DV);
        float4 v1 = *(const float4*)(vpb + (size_t)(r+8)*DV);
        float4 v2 = *(const float4*)(vpb + (size_t)(r+16)*DV);
        float4 v3 = *(const float4*)(vpb + (size_t)(r+24)*DV);
        cacc.x += a0*v0.x + a1*v1.x + a2*v2.x + a3*v3.x;
        cacc.y += a0*v0.y + a1*v1.y + a2*v2.y + a3*v3.y;
        cacc.z += a0*v0.z + a1*v1.z + a2*v2.z + a3*v3.z;
        cacc.w += a0*v0.w + a1*v1.w + a2*v2.w + a3*v3.w;
      }
      for (; r < L; r += 8){
        float a = e_s[r];
        float4 vv4 = *(const float4*)(vpb + (size_t)r*DV);
        cacc.x += a*vv4.x; cacc.y += a*vv4.y; cacc.z += a*vv4.z; cacc.w += a*vv4.w;
      }
    }
  }
  *(float4*)&ctxp[wv][lane*4] = cacc;
  __syncthreads();
  if (tid < DV){
    float cv = 0.f;
    #pragma unroll
    for (int q=0;q<8;++q) cv += ctxp[q][tid];
    ctx_s[tid] = cv;
    ctx[(size_t)n*DV + tid] = cv;
  }
  __syncthreads();
  #pragma unroll
  for (int vb2=0; vb2<2; ++vb2){
    int vvv = vb2*32 + (tid>>4);
    if (vvv < NV){
      int kbase = (tid&15)*32;
      float s = 0.f;
      #pragma unroll
      for (int q=0;q<32;q+=4){
        float4 w4 = *(const float4*)(Wout + (size_t)vvv*512 + kbase + q);
        int k = kbase + q;
        const float* xs = (k < DK)? &h2s[k] : &ctx_s[k-DK];
        s += w4.x*xs[0] + w4.y*xs[1] + w4.z*xs[2] + w4.w*xs[3];
      }
      s += __shfl_xor(s,1); s += __shfl_xor(s,2); s += __shfl_xor(s,4); s += __shfl_xor(s,8);
      if ((tid&15)==0) out[((size_t)n*STEPS + t)*NV + vvv] = s + b_out[vvv];
    }
  }
}

// ---------------- host ----------------
extern "C" void kernel_launch(void* const* d_in, const int* in_sizes, int n_in,
                              void* d_out, int out_size, void* d_ws, size_t ws_size,
                              hipStream_t stream)
{
  const float* enc_key = (const float*)d_in[0];
  const float* enc_val = (const float*)d_in[1];
  const int*   text    = (const int*)d_in[2];
  const int*   lens    = (const int*)d_in[3];
  const float* emb     = (const float*)d_in[5];
  const float* W_ih1   = (const float*)d_in[6];
  const float* W_hh1   = (const float*)d_in[7];
  const float* b_ih1   = (const float*)d_in[8];
  const float* b_hh1   = (const float*)d_in[9];
  const float* W_ih2   = (const float*)d_in[10];
  const float* W_hh2   = (const float*)d_in[11];
  const float* b_ih2   = (const float*)d_in[12];
  const float* b_hh2   = (const float*)d_in[13];
  const float* W_out   = (const float*)d_in[14];
  const float* b_out   = (const float*)d_in[15];
  float* out = (float*)d_out;

  char* ws = (char*)d_ws;
  size_t off = 0;
  auto alloc = [&](size_t bytes)->char*{
    char* p = ws + off; off = (off + bytes + 255) & ~(size_t)255; return p;
  };

  u16* Wc1h = (u16*)alloc((size_t)2048*K1*2);
  u16* Wc1l = (u16*)alloc((size_t)2048*K1*2);
  u16* Wc2h = (u16*)alloc((size_t)1024*K2*2);
  u16* Wc2l = (u16*)alloc((size_t)1024*K2*2);
  float* h1b = (float*)alloc((size_t)2*NB*HH*4);
  float* h2b = (float*)alloc((size_t)2*NB*DK*4);
  float* ctx = (float*)alloc((size_t)NB*DV*4);
  float* c1  = (float*)alloc((size_t)NB*HH*4);
  float* c2  = (float*)alloc((size_t)NB*DK*4);

  // zero recurrent state (contiguous block h1b..c2)
  size_t zbytes = (char*)c2 + (size_t)NB*DK*4 - (char*)h1b;
  (void)hipMemsetAsync(h1b, 0, zbytes, stream);

  // f16 K/V copies if workspace allows (R16-proven: absmax 0.0156)
  const size_t encElems = (size_t)NB*TE*DK;
  u16 *keyh = nullptr, *valh = nullptr;
  bool f16kv = (ws_size - off) >= (encElems*2*2 + 1024);
  if (f16kv){
    keyh = (u16*)alloc(encElems*2);
    valh = (u16*)alloc(encElems*2);
    int n8 = (int)(encElems/8);
    conv_f16<<<(n8+255)/256, 256, 0, stream>>>(keyh, enc_key, n8);
    conv_f16<<<(n8+255)/256, 256, 0, stream>>>(valh, enc_val, n8);
  }

  {
    int t8 = 2048*K1/8;
    conv_cat_split<<<(t8+255)/256, 256, 0, stream>>>(Wc1h, Wc1l, W_ih1, W_hh1, 768, 512, t8);
  }
  {
    int t8 = 1024*K2/8;
    conv_cat_split<<<(t8+255)/256, 256, 0, stream>>>(Wc2h, Wc2l, W_ih2, W_hh2, 512, 256, t8);
  }

  for (int t=0; t<STEPS; ++t){
    int par = t&1;
    lstm1_k<<<256, 512, 0, stream>>>(text, t, par, emb, ctx, h1b, c1, Wc1h, Wc1l, b_ih1, b_hh1);
    lstm2_k<<<128, 512, 0, stream>>>(par, h1b, h2b, c2, Wc2h, Wc2l, b_ih2, b_hh2);
    if (f16kv)
      attn_k<true><<<256, 512, 0, stream>>>(keyh, valh, lens, h2b, par, ctx, W_out, b_out, out, t);
    else
      attn_k<false><<<256, 512, 0, stream>>>(enc_key, enc_val, lens, h2b, par, ctx, W_out, b_out, out, t);
  }
}

// Round 20
// 19176.151 us; speedup vs baseline: 1.2450x; 1.0010x over previous
//
#include <hip/hip_runtime.h>

typedef unsigned short u16;
typedef __attribute__((ext_vector_type(8))) short short8;
typedef __attribute__((ext_vector_type(4))) float f32x4;
typedef __attribute__((ext_vector_type(8))) _Float16 h16x8;
typedef __attribute__((ext_vector_type(4))) _Float16 h16x4;

#define NB 256      // batch
#define TE 512      // encoder T
#define DK 256      // key dim
#define DV 256      // value dim
#define HH 512      // hidden
#define NV 35       // vocab
#define VOC 35
#define STEPS 300
#define TLEN 301
#define K1 1280     // LSTM1 inner dim: emb(512) + ctx(256) + h1(512)
#define K2 768      // LSTM2 inner dim: h1(512) + h2(256)

__device__ __forceinline__ float bf2f(u16 u){ return __uint_as_float(((unsigned)u)<<16); }
__device__ __forceinline__ u16 f2bf(float f){
  unsigned u = __float_as_uint(f);
  u += 0x7fffu + ((u>>16)&1u);   // RNE
  return (u16)(u>>16);
}
__device__ __forceinline__ void splitbf(float f, short& hi, short& lo){
  u16 h = f2bf(f);
  float r = f - bf2f(h);
  hi = (short)h; lo = (short)f2bf(r);
}
__device__ __forceinline__ float sigm(float x){ return 1.f/(1.f+expf(-x)); }

// ---------------- conversion kernels (once per launch) ----------------
__global__ void conv_cat_split(u16* __restrict__ dhi, u16* __restrict__ dlo,
                               const float* __restrict__ s1, const float* __restrict__ s2,
                               int k1, int k2, int total8){
  int i = blockIdx.x*blockDim.x + threadIdx.x;
  if (i >= total8) return;
  int ktot = k1 + k2;
  long e = (long)i*8;
  int r = (int)(e / ktot); int k = (int)(e - (long)r*ktot);
  const float* s = (k < k1) ? (s1 + (size_t)r*k1 + k) : (s2 + (size_t)r*k2 + (k-k1));
  short8 oh, ol;
  #pragma unroll
  for (int q=0;q<8;++q){ short h,l; splitbf(s[q],h,l); oh[q]=h; ol[q]=l; }
  *(short8*)(dhi + e) = oh;
  *(short8*)(dlo + e) = ol;
}

// plain f32 -> hi/lo bf16 split (for emb table)
__global__ void conv_split(u16* __restrict__ dhi, u16* __restrict__ dlo,
                           const float* __restrict__ src, int n8){
  int i = blockIdx.x*blockDim.x + threadIdx.x;
  if (i >= n8) return;
  const float* s = src + (size_t)i*8;
  short8 oh, ol;
  #pragma unroll
  for (int q=0;q<8;++q){ short h,l; splitbf(s[q],h,l); oh[q]=h; ol[q]=l; }
  *(short8*)(dhi + (size_t)i*8) = oh;
  *(short8*)(dlo + (size_t)i*8) = ol;
}

__global__ void conv_f16(u16* __restrict__ dst, const float* __restrict__ src, int n8){
  int i = blockIdx.x*blockDim.x + threadIdx.x;
  if (i >= n8) return;
  const float* s = src + (size_t)i*8;
  h16x8 o;
  #pragma unroll
  for (int q=0;q<8;++q) o[q] = (_Float16)s[q];
  *(h16x8*)(dst + (size_t)i*8) = o;
}

// ---------------- LSTM1: K-split 8-wave GEMM + cell update ----------------
// A inputs pre-split hi/lo (emb table, ctx, h1) -> direct short8 loads,
// zero split-VALU in the K-loop. Numerically identical to R12/R19.
__global__ __launch_bounds__(512) void lstm1_k(
  const int* __restrict__ text, int t, int par,
  const u16* __restrict__ embh, const u16* __restrict__ embl,
  const u16* __restrict__ ctxh, const u16* __restrict__ ctxl,
  u16* __restrict__ h1h, u16* __restrict__ h1l,
  float* __restrict__ c1,
  const u16* __restrict__ Whi, const u16* __restrict__ Wlo,
  const float* __restrict__ b_ih, const float* __restrict__ b_hh)
{
  __shared__ __align__(16) float accS[4][4][2][64][4];   // [gate][kq][nh][lane][reg] 32KB
  const u16* h1h_old = h1h + (size_t)par*NB*HH;
  const u16* h1l_old = h1l + (size_t)par*NB*HH;
  u16* h1h_new = h1h + (size_t)(par^1)*NB*HH;
  u16* h1l_new = h1l + (size_t)(par^1)*NB*HH;
  int b = blockIdx.x;
  int jt  = (b&7)*4 + ((b>>3)&3);     // XCD swizzle: W slice L2-resident per XCD
  int jh0 = jt*16;
  int n0  = (b>>5)*32;
  int tid = threadIdx.x, w = tid>>6, l = tid&63;
  int nh = w&1, kq = w>>1;
  int kbase = kq*(K1/4);
  int col = l&15, kc = l>>4, ofs = kc*8;

  int arow = n0 + nh*16 + col;
  size_t embo = (size_t)text[arow*TLEN + t]*HH;
  const u16* aeh = embh + embo;
  const u16* ael = embl + embo;
  const u16* ach = ctxh + (size_t)arow*DV;
  const u16* acl = ctxl + (size_t)arow*DV;
  const u16* a1h = h1h_old + (size_t)arow*HH;
  const u16* a1l = h1l_old + (size_t)arow*HH;

  const u16* pBh[4]; const u16* pBl[4];
  #pragma unroll
  for (int g=0; g<4; ++g){
    size_t r = (size_t)(g*512 + jh0 + col)*K1 + kbase + ofs;
    pBh[g] = Whi + r; pBl[g] = Wlo + r;
  }

  f32x4 acc[4];
  #pragma unroll
  for (int g=0;g<4;++g) acc[g] = (f32x4){0.f,0.f,0.f,0.f};

  short8 avh, avl, rbh[4], rbl[4];
  {
    int k = kbase;
    const u16 *sh, *sl;
    if (k<512){ sh=aeh+k; sl=ael+k; }
    else if (k<768){ sh=ach+(k-512); sl=acl+(k-512); }
    else { sh=a1h+(k-768); sl=a1l+(k-768); }
    avh = *(const short8*)(sh+ofs); avl = *(const short8*)(sl+ofs);
    #pragma unroll
    for (int g=0;g<4;++g){ rbh[g] = *(const short8*)(pBh[g]); rbl[g] = *(const short8*)(pBl[g]); }
  }

  for (int k0=0; k0<K1/4; k0+=32){
    short8 cah = avh, cal = avl;
    short8 cbh[4], cbl[4];
    #pragma unroll
    for (int g=0;g<4;++g){ cbh[g]=rbh[g]; cbl[g]=rbl[g]; }
    int k0n = k0 + 32;
    if (k0n < K1/4){
      int k = kbase + k0n;
      const u16 *sh, *sl;
      if (k<512){ sh=aeh+k; sl=ael+k; }
      else if (k<768){ sh=ach+(k-512); sl=acl+(k-512); }
      else { sh=a1h+(k-768); sl=a1l+(k-768); }
      avh = *(const short8*)(sh+ofs); avl = *(const short8*)(sl+ofs);
      #pragma unroll
      for (int g=0;g<4;++g){ rbh[g] = *(const short8*)(pBh[g] + k0n); rbl[g] = *(const short8*)(pBl[g] + k0n); }
    }
    #pragma unroll
    for (int g=0; g<4; ++g){
      acc[g] = __builtin_amdgcn_mfma_f32_16x16x32_bf16(cah, cbh[g], acc[g], 0,0,0);
      acc[g] = __builtin_amdgcn_mfma_f32_16x16x32_bf16(cal, cbh[g], acc[g], 0,0,0);
      acc[g] = __builtin_amdgcn_mfma_f32_16x16x32_bf16(cah, cbl[g], acc[g], 0,0,0);
    }
  }

  #pragma unroll
  for (int g=0;g<4;++g) *(f32x4*)&accS[g][kq][nh][l][0] = acc[g];
  __syncthreads();

  int en = tid>>4, ej = tid&15;
  int nhe = en>>4, r = en&15;
  int lane_e = ((r>>2)<<4) | ej, reg = r&3;
  float gv4[4];
  #pragma unroll
  for (int g=0;g<4;++g){
    gv4[g] = accS[g][0][nhe][lane_e][reg] + accS[g][1][nhe][lane_e][reg]
           + accS[g][2][nhe][lane_e][reg] + accS[g][3][nhe][lane_e][reg];
  }
  int jh = jh0 + ej;
  float bi  = b_ih[jh]      + b_hh[jh];
  float bff = b_ih[HH+jh]   + b_hh[HH+jh];
  float bg  = b_ih[2*HH+jh] + b_hh[2*HH+jh];
  float bo  = b_ih[3*HH+jh] + b_hh[3*HH+jh];
  size_t idx = (size_t)(n0+en)*HH + jh;
  float iv = sigm(gv4[0]+bi);
  float fv = sigm(gv4[1]+bff);
  float gg = tanhf(gv4[2]+bg);
  float ov = sigm(gv4[3]+bo);
  float cn = fv*c1[idx] + iv*gg;
  c1[idx] = cn;
  float hval = ov*tanhf(cn);
  short hh, hl; splitbf(hval, hh, hl);
  h1h_new[idx] = (u16)hh;
  h1l_new[idx] = (u16)hl;
}

// ---------------- LSTM2: K-split 8-wave, K=768 ----------------
__global__ __launch_bounds__(512) void lstm2_k(
  int par,
  const u16* __restrict__ h1h, const u16* __restrict__ h1l,
  u16* __restrict__ h2h, u16* __restrict__ h2l,
  float* __restrict__ c2,
  const u16* __restrict__ Whi, const u16* __restrict__ Wlo,
  const float* __restrict__ b_ih, const float* __restrict__ b_hh)
{
  __shared__ __align__(16) float accS[4][4][2][64][4];
  const u16* a1hB = h1h + (size_t)(par^1)*NB*HH;
  const u16* a1lB = h1l + (size_t)(par^1)*NB*HH;
  const u16* a2hB = h2h + (size_t)par*NB*DK;
  const u16* a2lB = h2l + (size_t)par*NB*DK;
  u16* h2h_new = h2h + (size_t)(par^1)*NB*DK;
  u16* h2l_new = h2l + (size_t)(par^1)*NB*DK;
  int b = blockIdx.x;
  int jt  = (b&7)*2 + ((b>>3)&1);
  int jh0 = jt*16;
  int n0  = (b>>4)*32;
  int tid = threadIdx.x, w = tid>>6, l = tid&63;
  int nh = w&1, kq = w>>1;
  int kbase = kq*(K2/4);
  int col = l&15, kc = l>>4, ofs = kc*8;

  int arow = n0 + nh*16 + col;
  const u16* a1h = a1hB + (size_t)arow*HH;
  const u16* a1l = a1lB + (size_t)arow*HH;
  const u16* a2h = a2hB + (size_t)arow*DK;
  const u16* a2l = a2lB + (size_t)arow*DK;

  const u16* pBh[4]; const u16* pBl[4];
  #pragma unroll
  for (int g=0; g<4; ++g){
    size_t r = (size_t)(g*256 + jh0 + col)*K2 + kbase + ofs;
    pBh[g] = Whi + r; pBl[g] = Wlo + r;
  }

  f32x4 acc[4];
  #pragma unroll
  for (int g=0;g<4;++g) acc[g] = (f32x4){0.f,0.f,0.f,0.f};

  short8 avh, avl, rbh[4], rbl[4];
  {
    int k = kbase;
    const u16 *sh, *sl;
    if (k<512){ sh=a1h+k; sl=a1l+k; }
    else { sh=a2h+(k-512); sl=a2l+(k-512); }
    avh = *(const short8*)(sh+ofs); avl = *(const short8*)(sl+ofs);
    #pragma unroll
    for (int g=0;g<4;++g){ rbh[g] = *(const short8*)(pBh[g]); rbl[g] = *(const short8*)(pBl[g]); }
  }

  for (int k0=0; k0<K2/4; k0+=32){
    short8 cah = avh, cal = avl;
    short8 cbh[4], cbl[4];
    #pragma unroll
    for (int g=0;g<4;++g){ cbh[g]=rbh[g]; cbl[g]=rbl[g]; }
    int k0n = k0 + 32;
    if (k0n < K2/4){
      int k = kbase + k0n;
      const u16 *sh, *sl;
      if (k<512){ sh=a1h+k; sl=a1l+k; }
      else { sh=a2h+(k-512); sl=a2l+(k-512); }
      avh = *(const short8*)(sh+ofs); avl = *(const short8*)(sl+ofs);
      #pragma unroll
      for (int g=0;g<4;++g){ rbh[g] = *(const short8*)(pBh[g] + k0n); rbl[g] = *(const short8*)(pBl[g] + k0n); }
    }
    #pragma unroll
    for (int g=0; g<4; ++g){
      acc[g] = __builtin_amdgcn_mfma_f32_16x16x32_bf16(cah, cbh[g], acc[g], 0,0,0);
      acc[g] = __builtin_amdgcn_mfma_f32_16x16x32_bf16(cal, cbh[g], acc[g], 0,0,0);
      acc[g] = __builtin_amdgcn_mfma_f32_16x16x32_bf16(cah, cbl[g], acc[g], 0,0,0);
    }
  }

  #pragma unroll
  for (int g=0;g<4;++g) *(f32x4*)&accS[g][kq][nh][l][0] = acc[g];
  __syncthreads();

  int en = tid>>4, ej = tid&15;
  int nhe = en>>4, r = en&15;
  int lane_e = ((r>>2)<<4) | ej, reg = r&3;
  float gv4[4];
  #pragma unroll
  for (int g=0;g<4;++g){
    gv4[g] = accS[g][0][nhe][lane_e][reg] + accS[g][1][nhe][lane_e][reg]
           + accS[g][2][nhe][lane_e][reg] + accS[g][3][nhe][lane_e][reg];
  }
  int jh = jh0 + ej;
  float bi  = b_ih[jh]      + b_hh[jh];
  float bff = b_ih[DK+jh]   + b_hh[DK+jh];
  float bg  = b_ih[2*DK+jh] + b_hh[2*DK+jh];
  float bo  = b_ih[3*DK+jh] + b_hh[3*DK+jh];
  size_t idx = (size_t)(n0+en)*DK + jh;
  float iv = sigm(gv4[0]+bi);
  float fv = sigm(gv4[1]+bff);
  float gg = tanhf(gv4[2]+bg);
  float ov = sigm(gv4[3]+bo);
  float cn = fv*c2[idx] + iv*gg;
  c2[idx] = cn;
  float hval = ov*tanhf(cn);
  short hh, hl; splitbf(hval, hh, hl);
  h2h_new[idx] = (u16)hh;
  h2l_new[idx] = (u16)hl;
}

// ---------------- attention + softmax + ctx + output projection (R19-proven) ----------------
template<bool F16>
__global__ __launch_bounds__(512) void attn_k(
  const void* __restrict__ keysv, const void* __restrict__ valsv,
  const int* __restrict__ lens,
  const u16* __restrict__ h2h, const u16* __restrict__ h2l, int par,
  u16* __restrict__ ctxh, u16* __restrict__ ctxl,
  const float* __restrict__ Wout, const float* __restrict__ b_out,
  float* __restrict__ out, int t)
{
  __shared__ float h2s[DK];
  __shared__ float e_s[TE];
  __shared__ float ctx_s[DV];
  __shared__ float ctxp[8][DV];
  __shared__ float red_s[16];
  int n = blockIdx.x, tid = threadIdx.x;
  int wv = tid>>6, lane = tid&63;
  int L = lens[n] >> 3;
  if (tid < DK){
    size_t hidx = (size_t)(par^1)*NB*DK + (size_t)n*DK + tid;
    h2s[tid] = bf2f(h2h[hidx]) + bf2f(h2l[hidx]);   // exact reconstruction
  }
  __syncthreads();
  float qreg[32];
  {
    int off = (lane&7)*32;
    #pragma unroll
    for (int q=0;q<32;q+=4){
      float4 v4 = *(const float4*)&h2s[off+q];
      qreg[q]=v4.x; qreg[q+1]=v4.y; qreg[q+2]=v4.z; qreg[q+3]=v4.w;
    }
  }
  // ---- QK: 8 lanes/row, 64 row-slots, unroll 2 rows/iter ----
  {
    int r = wv*8 + (lane>>3);
    int off = (lane&7)*32;
    if (F16){
      const u16* kb = (const u16*)keysv + (size_t)n*TE*DK + off;
      for (; r+64 < L; r += 128){
        const u16* kr0 = kb + (size_t)r*DK;
        const u16* kr1 = kb + (size_t)(r+64)*DK;
        h16x8 k0[4], k1[4];
        #pragma unroll
        for (int q=0;q<4;++q){ k0[q] = *(const h16x8*)(kr0 + q*8); }
        #pragma unroll
        for (int q=0;q<4;++q){ k1[q] = *(const h16x8*)(kr1 + q*8); }
        float s0=0.f, s1=0.f;
        #pragma unroll
        for (int q=0;q<4;++q){
          #pragma unroll
          for (int j=0;j<8;++j){
            s0 += (float)k0[q][j]*qreg[q*8+j];
            s1 += (float)k1[q][j]*qreg[q*8+j];
          }
        }
        s0 += __shfl_xor(s0,1); s0 += __shfl_xor(s0,2); s0 += __shfl_xor(s0,4);
        s1 += __shfl_xor(s1,1); s1 += __shfl_xor(s1,2); s1 += __shfl_xor(s1,4);
        if ((lane&7)==0){ e_s[r] = s0; e_s[r+64] = s1; }
      }
      for (; r < L; r += 64){
        const u16* kr = kb + (size_t)r*DK;
        float s = 0.f;
        #pragma unroll
        for (int q=0;q<4;++q){
          h16x8 kv = *(const h16x8*)(kr + q*8);
          #pragma unroll
          for (int j=0;j<8;++j) s += (float)kv[j]*qreg[q*8+j];
        }
        s += __shfl_xor(s,1); s += __shfl_xor(s,2); s += __shfl_xor(s,4);
        if ((lane&7)==0) e_s[r] = s;
      }
    } else {
      const float* kb = (const float*)keysv + (size_t)n*TE*DK + off;
      for (; r+64 < L; r += 128){
        const float* kr0 = kb + (size_t)r*DK;
        const float* kr1 = kb + (size_t)(r+64)*DK;
        float4 k0[8], k1[8];
        #pragma unroll
        for (int q=0;q<8;++q){ k0[q] = *(const float4*)(kr0 + q*4); }
        #pragma unroll
        for (int q=0;q<8;++q){ k1[q] = *(const float4*)(kr1 + q*4); }
        float s0=0.f, s1=0.f;
        #pragma unroll
        for (int q=0;q<8;++q){
          s0 += k0[q].x*qreg[q*4] + k0[q].y*qreg[q*4+1] + k0[q].z*qreg[q*4+2] + k0[q].w*qreg[q*4+3];
          s1 += k1[q].x*qreg[q*4] + k1[q].y*qreg[q*4+1] + k1[q].z*qreg[q*4+2] + k1[q].w*qreg[q*4+3];
        }
        s0 += __shfl_xor(s0,1); s0 += __shfl_xor(s0,2); s0 += __shfl_xor(s0,4);
        s1 += __shfl_xor(s1,1); s1 += __shfl_xor(s1,2); s1 += __shfl_xor(s1,4);
        if ((lane&7)==0){ e_s[r] = s0; e_s[r+64] = s1; }
      }
      for (; r < L; r += 64){
        const float* kr = kb + (size_t)r*DK;
        float s = 0.f;
        #pragma unroll
        for (int q=0;q<8;++q){
          float4 kv = *(const float4*)(kr + q*4);
          s += kv.x*qreg[q*4] + kv.y*qreg[q*4+1] + kv.z*qreg[q*4+2] + kv.w*qreg[q*4+3];
        }
        s += __shfl_xor(s,1); s += __shfl_xor(s,2); s += __shfl_xor(s,4);
        if ((lane&7)==0) e_s[r] = s;
      }
    }
  }
  __syncthreads();
  float v = (tid < L) ? e_s[tid] : -1e30f;
  float m = v;
  #pragma unroll
  for (int o=1;o<64;o<<=1) m = fmaxf(m, __shfl_xor(m,o));
  if (lane==0) red_s[wv] = m;
  __syncthreads();
  m = red_s[0];
  #pragma unroll
  for (int q=1;q<8;++q) m = fmaxf(m, red_s[q]);
  float p = (tid < L) ? expf(v-m) : 0.f;
  float sm = p;
  #pragma unroll
  for (int o=1;o<64;o<<=1) sm += __shfl_xor(sm,o);
  if (lane==0) red_s[8+wv] = sm;
  __syncthreads();
  sm = red_s[8];
  #pragma unroll
  for (int q=1;q<8;++q) sm += red_s[8+q];
  e_s[tid] = p * (1.f/sm);
  __syncthreads();
  // ---- PV: wave-strided rows, unroll 4 rows/iter ----
  float4 cacc = {0.f,0.f,0.f,0.f};
  {
    int r = wv;
    if (F16){
      const u16* vpb = (const u16*)valsv + (size_t)n*TE*DV + lane*4;
      for (; r+24 < L; r += 32){
        float a0=e_s[r], a1=e_s[r+8], a2=e_s[r+16], a3=e_s[r+24];
        h16x4 v0 = *(const h16x4*)(vpb + (size_t)r*DV);
        h16x4 v1 = *(const h16x4*)(vpb + (size_t)(r+8)*DV);
        h16x4 v2 = *(const h16x4*)(vpb + (size_t)(r+16)*DV);
        h16x4 v3 = *(const h16x4*)(vpb + (size_t)(r+24)*DV);
        cacc.x += a0*(float)v0[0] + a1*(float)v1[0] + a2*(float)v2[0] + a3*(float)v3[0];
        cacc.y += a0*(float)v0[1] + a1*(float)v1[1] + a2*(float)v2[1] + a3*(float)v3[1];
        cacc.z += a0*(float)v0[2] + a1*(float)v1[2] + a2*(float)v2[2] + a3*(float)v3[2];
        cacc.w += a0*(float)v0[3] + a1*(float)v1[3] + a2*(float)v2[3] + a3*(float)v3[3];
      }
      for (; r < L; r += 8){
        float a = e_s[r];
        h16x4 vv = *(const h16x4*)(vpb + (size_t)r*DV);
        cacc.x += a*(float)vv[0]; cacc.y += a*(float)vv[1];
        cacc.z += a*(float)vv[2]; cacc.w += a*(float)vv[3];
      }
    } else {
      const float* vpb = (const float*)valsv + (size_t)n*TE*DV + lane*4;
      for (; r+24 < L; r += 32){
        float a0=e_s[r], a1=e_s[r+8], a2=e_s[r+16], a3=e_s[r+24];
        float4 v0 = *(const float4*)(vpb + (size_t)r*DV);
        float4 v1 = *(const float4*)(vpb + (size_t)(r+8)*DV);
        float4 v2 = *(const float4*)(vpb + (size_t)(r+16)*DV);
        float4 v3 = *(const float4*)(vpb + (size_t)(r+24)*DV);
        cacc.x += a0*v0.x + a1*v1.x + a2*v2.x + a3*v3.x;
        cacc.y += a0*v0.y + a1*v1.y + a2*v2.y + a3*v3.y;
        cacc.z += a0*v0.z + a1*v1.z + a2*v2.z + a3*v3.z;
        cacc.w += a0*v0.w + a1*v1.w + a2*v2.w + a3*v3.w;
      }
      for (; r < L; r += 8){
        float a = e_s[r];
        float4 vv4 = *(const float4*)(vpb + (size_t)r*DV);
        cacc.x += a*vv4.x; cacc.y += a*vv4.y; cacc.z += a*vv4.z; cacc.w += a*vv4.w;
      }
    }
  }
  *(float4*)&ctxp[wv][lane*4] = cacc;
  __syncthreads();
  if (tid < DV){
    float cv = 0.f;
    #pragma unroll
    for (int q=0;q<8;++q) cv += ctxp[q][tid];
    ctx_s[tid] = cv;
    short hh, hl; splitbf(cv, hh, hl);
    ctxh[(size_t)n*DV + tid] = (u16)hh;
    ctxl[(size_t)n*DV + tid] = (u16)hl;
  }
  __syncthreads();
  #pragma unroll
  for (int vb2=0; vb2<2; ++vb2){
    int vvv = vb2*32 + (tid>>4);
    if (vvv < NV){
      int kbase = (tid&15)*32;
      float s = 0.f;
      #pragma unroll
      for (int q=0;q<32;q+=4){
        float4 w4 = *(const float4*)(Wout + (size_t)vvv*512 + kbase + q);
        int k = kbase + q;
        const float* xs = (k < DK)? &h2s[k] : &ctx_s[k-DK];
        s += w4.x*xs[0] + w4.y*xs[1] + w4.z*xs[2] + w4.w*xs[3];
      }
      s += __shfl_xor(s,1); s += __shfl_xor(s,2); s += __shfl_xor(s,4); s += __shfl_xor(s,8);
      if ((tid&15)==0) out[((size_t)n*STEPS + t)*NV + vvv] = s + b_out[vvv];
    }
  }
}

// ---------------- host ----------------
extern "C" void kernel_launch(void* const* d_in, const int* in_sizes, int n_in,
                              void* d_out, int out_size, void* d_ws, size_t ws_size,
                              hipStream_t stream)
{
  const float* enc_key = (const float*)d_in[0];
  const float* enc_val = (const float*)d_in[1];
  const int*   text    = (const int*)d_in[2];
  const int*   lens    = (const int*)d_in[3];
  const float* emb     = (const float*)d_in[5];
  const float* W_ih1   = (const float*)d_in[6];
  const float* W_hh1   = (const float*)d_in[7];
  const float* b_ih1   = (const float*)d_in[8];
  const float* b_hh1   = (const float*)d_in[9];
  const float* W_ih2   = (const float*)d_in[10];
  const float* W_hh2   = (const float*)d_in[11];
  const float* b_ih2   = (const float*)d_in[12];
  const float* b_hh2   = (const float*)d_in[13];
  const float* W_out   = (const float*)d_in[14];
  const float* b_out   = (const float*)d_in[15];
  float* out = (float*)d_out;

  char* ws = (char*)d_ws;
  size_t off = 0;
  auto alloc = [&](size_t bytes)->char*{
    char* p = ws + off; off = (off + bytes + 255) & ~(size_t)255; return p;
  };

  u16* Wc1h = (u16*)alloc((size_t)2048*K1*2);
  u16* Wc1l = (u16*)alloc((size_t)2048*K1*2);
  u16* Wc2h = (u16*)alloc((size_t)1024*K2*2);
  u16* Wc2l = (u16*)alloc((size_t)1024*K2*2);
  u16* embh = (u16*)alloc((size_t)VOC*HH*2);
  u16* embl = (u16*)alloc((size_t)VOC*HH*2);
  // recurrent state (hi/lo bf16) + cells (f32) — zeroed below
  u16* h1h = (u16*)alloc((size_t)2*NB*HH*2);
  u16* h1l = (u16*)alloc((size_t)2*NB*HH*2);
  u16* h2h = (u16*)alloc((size_t)2*NB*DK*2);
  u16* h2l = (u16*)alloc((size_t)2*NB*DK*2);
  u16* ctxh = (u16*)alloc((size_t)NB*DV*2);
  u16* ctxl = (u16*)alloc((size_t)NB*DV*2);
  float* c1  = (float*)alloc((size_t)NB*HH*4);
  float* c2  = (float*)alloc((size_t)NB*DK*4);

  // zero recurrent state (bf16 0x0000 == 0.0f) — contiguous h1h..c2
  size_t zbytes = ((char*)c2 + (size_t)NB*DK*4) - (char*)h1h;
  (void)hipMemsetAsync(h1h, 0, zbytes, stream);

  // f16 K/V copies if workspace allows (R16-proven: absmax 0.0156)
  const size_t encElems = (size_t)NB*TE*DK;
  u16 *keyh = nullptr, *valh = nullptr;
  bool f16kv = (ws_size - off) >= (encElems*2*2 + 1024);
  if (f16kv){
    keyh = (u16*)alloc(encElems*2);
    valh = (u16*)alloc(encElems*2);
    int n8 = (int)(encElems/8);
    conv_f16<<<(n8+255)/256, 256, 0, stream>>>(keyh, enc_key, n8);
    conv_f16<<<(n8+255)/256, 256, 0, stream>>>(valh, enc_val, n8);
  }

  {
    int t8 = 2048*K1/8;
    conv_cat_split<<<(t8+255)/256, 256, 0, stream>>>(Wc1h, Wc1l, W_ih1, W_hh1, 768, 512, t8);
  }
  {
    int t8 = 1024*K2/8;
    conv_cat_split<<<(t8+255)/256, 256, 0, stream>>>(Wc2h, Wc2l, W_ih2, W_hh2, 512, 256, t8);
  }
  {
    int n8 = VOC*HH/8;
    conv_split<<<(n8+255)/256, 256, 0, stream>>>(embh, embl, emb, n8);
  }

  for (int t=0; t<STEPS; ++t){
    int par = t&1;
    lstm1_k<<<256, 512, 0, stream>>>(text, t, par, embh, embl, ctxh, ctxl,
                                     h1h, h1l, c1, Wc1h, Wc1l, b_ih1, b_hh1);
    lstm2_k<<<128, 512, 0, stream>>>(par, h1h, h1l, h2h, h2l, c2, Wc2h, Wc2l, b_ih2, b_hh2);
    if (f16kv)
      attn_k<true><<<256, 512, 0, stream>>>(keyh, valh, lens, h2h, h2l, par,
                                            ctxh, ctxl, W_out, b_out, out, t);
    else
      attn_k<false><<<256, 512, 0, stream>>>(enc_key, enc_val, lens, h2h, h2l, par,
                                             ctxh, ctxl, W_out, b_out, out, t);
  }
}